// Round 6
// baseline (735.985 us; speedup 1.0000x reference)
//
#include <hip/hip_runtime.h>
#include <hip/hip_bf16.h>

typedef __bf16 bf16x8 __attribute__((ext_vector_type(8)));
typedef __bf16 bf16x4 __attribute__((ext_vector_type(4)));
typedef float f32x4 __attribute__((ext_vector_type(4)));

#define AS1P(p) ((__attribute__((address_space(1))) void*)(void*)(p))
#define AS3P(p) ((__attribute__((address_space(3))) void*)(p))

// ---------------------------------------------------------------------------
// 128x128 bf16 GEMM (projections / thin-N): BK=32 DOUBLE-buffer (32KB LDS ->
// 5 blocks/CU, 20 waves/CU), 2-phase K-loop [issue next -> 16 mfma ->
// vmcnt(0) -> barrier]. Full drain is covered by inter-block overlap at
// 5 blocks/CU (m114). Projection grid 1280 = exactly 5*256: zero tail.
// V-columns (col >= vcol0) are written TRANSPOSED to Vt ([P, M] layout).
// ---------------------------------------------------------------------------
__global__ __launch_bounds__(256, 5) void gemm_bt(
    const __hip_bfloat16* __restrict__ A, int lda,
    const __hip_bfloat16* __restrict__ Bt, int ldb,
    int M, int N, int K, int ldc,
    const float* __restrict__ bias, int bias_mode,   // 0 none, 1 per-col, 2 per-row
    float scale,
    const float* __restrict__ residual,              // f32 [M,ldc] or null
    int relu, int causal_skip, int trapezoid, int ksplit,
    float* __restrict__ Cf, __hip_bfloat16* __restrict__ Cb,
    int vcol0, __hip_bfloat16* __restrict__ Vt, int ldvt,
    // fused second GEMM (blocks with nb >= nsplit1); shares lda/M/K
    int nsplit1, const __hip_bfloat16* __restrict__ A2,
    const __hip_bfloat16* __restrict__ Bt2, int ldb2, int ldc2,
    const float* __restrict__ bias2, __hip_bfloat16* __restrict__ Cb2,
    int vcol0_2, __hip_bfloat16* __restrict__ Vt2, int ldvt2)
{
    int nb = blockIdx.x;
    int mb = blockIdx.y;
    {   // XCD-aware 2D-region swizzle (identity if shape not divisible)
        const int gx = gridDim.x, gy = gridDim.y;
        if ((gx & 3) == 0 && (gy & 1) == 0) {
            const int id = mb * gx + nb;
            const int X  = id & 7;
            const int L  = id >> 3;
            const int rn = gx >> 2, rm = gy >> 1;
            const int nb_l = L / rm, mb_l = L - nb_l * rm;
            nb = (X & 3) * rn + nb_l;
            mb = (X >> 2) * rm + mb_l;
        }
    }
    if (nsplit1 && nb >= nsplit1) {
        A = A2; Bt = Bt2; ldb = ldb2; ldc = ldc2; bias = bias2;
        Cb = Cb2; Cf = nullptr; residual = nullptr;
        vcol0 = vcol0_2; Vt = Vt2; ldvt = ldvt2;
        nb -= nsplit1;
    }
    const int m_base = mb * 128;
    const int n_base = nb * 128;
    if (causal_skip && (n_base > m_base + 127)) return;
    int Kend = K;
    if (trapezoid) { int kl = m_base + 128; Kend = kl < K ? kl : K; }
    int kb = 0, ke = Kend;
    if (ksplit) {
        kb = blockIdx.z * ksplit;
        int k2 = kb + ksplit; ke = k2 < Kend ? k2 : Kend;
        if (kb >= ke) return;
        Cb += (size_t)blockIdx.z * M * ldc;
        Cf = nullptr;
    }
    const int nt = (ke - kb) >> 5;

    __shared__ __align__(16) __hip_bfloat16 Lds[2][8192];

    const int tid  = threadIdx.x;
    const int lane = tid & 63;
    const int wave = tid >> 6;
    const int wm = (wave >> 1) * 64;
    const int wn = (wave & 1) * 64;

    f32x4 acc[4][4];
#pragma unroll
    for (int i = 0; i < 4; ++i)
#pragma unroll
        for (int j = 0; j < 4; ++j) acc[i][j] = f32x4{0.f, 0.f, 0.f, 0.f};

    const bool isA = wave < 2;
    const __hip_bfloat16* G = isA ? (A + (size_t)m_base * lda) : (Bt + (size_t)n_base * ldb);
    const int ldg = isA ? lda : ldb;
    const int q0 = (wave & 1) * 4;
    const int rsub = lane >> 2;
    const int cx   = (lane & 3) ^ ((lane >> 3) & 3);
    const size_t grow = (size_t)(q0 * 16 + rsub) * ldg + (size_t)cx * 8 + kb;
    const int ldsoff = (isA ? 0 : 4096) + q0 * 512;

    const int lrow = lane & 15;
    const int cph  = ((lane >> 4) ^ ((lrow >> 1) & 3)) * 8;

#define ISSUE_TILE(KT, STG)                                                      \
    {                                                                            \
        const __hip_bfloat16* g = G + grow + (size_t)(KT) * 32;                  \
        __hip_bfloat16* dst = &Lds[STG][ldsoff];                                 \
        _Pragma("unroll")                                                        \
        for (int q = 0; q < 4; ++q) {                                            \
            __builtin_amdgcn_global_load_lds(AS1P(g), AS3P(dst), 16, 0, 0);      \
            g += (size_t)16 * ldg; dst += 512;                                   \
        }                                                                        \
    }

    ISSUE_TILE(0, 0)
    __builtin_amdgcn_s_waitcnt(0x0F70);  // vmcnt(0)
    __builtin_amdgcn_s_barrier();

    int cur = 0;
    for (int kt = 0; kt < nt; ++kt) {
        __builtin_amdgcn_sched_barrier(0);
        if (kt + 1 < nt) ISSUE_TILE(kt + 1, cur ^ 1)
        __builtin_amdgcn_sched_barrier(0);

        bf16x8 af[4], bfv[4];
#pragma unroll
        for (int i = 0; i < 4; ++i)
            af[i] = *(const bf16x8*)&Lds[cur][(wm + i * 16 + lrow) * 32 + cph];
#pragma unroll
        for (int j = 0; j < 4; ++j)
            bfv[j] = *(const bf16x8*)&Lds[cur][4096 + (wn + j * 16 + lrow) * 32 + cph];
#pragma unroll
        for (int i = 0; i < 4; ++i)
#pragma unroll
            for (int j = 0; j < 4; ++j)
                acc[i][j] = __builtin_amdgcn_mfma_f32_16x16x32_bf16(af[i], bfv[j], acc[i][j], 0, 0, 0);

        __builtin_amdgcn_sched_barrier(0);
        if (kt + 1 < nt) {
            __builtin_amdgcn_s_waitcnt(0x0F70);  // vmcnt(0): next tile landed
            __builtin_amdgcn_s_barrier();
        }
        cur ^= 1;
    }
#undef ISSUE_TILE

    const int r0 = (lane >> 4) * 4;
    const int c0 = lane & 15;
    const bool vtrans = (n_base >= vcol0);   // vcol0 multiple of 128 -> block-uniform
#pragma unroll
    for (int i = 0; i < 4; ++i) {
#pragma unroll
        for (int j = 0; j < 4; ++j) {
            const int col = n_base + wn + j * 16 + c0;
            const int row0 = m_base + wm + i * 16 + r0;
            float vv[4];
#pragma unroll
            for (int r = 0; r < 4; ++r) {
                float v = acc[i][j][r] * scale;
                if (bias_mode == 1) v += bias[col];
                else if (bias_mode == 2) v += bias[row0 + r];
                if (relu) v = fmaxf(v, 0.f);
                vv[r] = v;
            }
            if (vtrans) {
                bf16x4 o = { (__bf16)vv[0], (__bf16)vv[1], (__bf16)vv[2], (__bf16)vv[3] };
                *(bf16x4*)(Vt + (size_t)(col - vcol0) * ldvt + row0) = o;
            } else {
#pragma unroll
                for (int r = 0; r < 4; ++r) {
                    const size_t idx = (size_t)(row0 + r) * ldc + col;
                    float v = vv[r];
                    if (residual) v += residual[idx];
                    if (Cf) Cf[idx] = v;
                    else    Cb[idx] = __float2bfloat16(v);
                }
            }
        }
    }
}

// ---------------------------------------------------------------------------
// 256x128 bf16 GEMM: 4 waves each 128x64, BK=32 triple-buffer (72KB LDS,
// 2 blocks/CU), depth-2 prefetch, single barrier per iter. Used for the
// ragged attention shapes (causal S1 / trapezoid AV1).
// ---------------------------------------------------------------------------
__global__ __launch_bounds__(256, 2) void gemm_bt2(
    const __hip_bfloat16* __restrict__ A, int lda,
    const __hip_bfloat16* __restrict__ Bt, int ldb,
    int M, int N, int K, int ldc,
    const float* __restrict__ bias, int bias_mode,
    float scale,
    int relu, int causal_skip, int trapezoid, int ksplit,
    __hip_bfloat16* __restrict__ Cb)
{
    int nb = blockIdx.x;
    int mb = blockIdx.y;
    {   // XCD-aware 2D-region swizzle
        const int gx = gridDim.x, gy = gridDim.y;
        if ((gx & 3) == 0 && (gy & 1) == 0) {
            const int id = mb * gx + nb;
            const int X  = id & 7;
            const int L  = id >> 3;
            const int rn = gx >> 2, rm = gy >> 1;
            const int nb_l = L / rm, mb_l = L - nb_l * rm;
            nb = (X & 3) * rn + nb_l;
            mb = (X >> 2) * rm + mb_l;
        }
    }
    const int m_base = mb * 256;
    const int n_base = nb * 128;
    if (causal_skip && (n_base > m_base + 255)) return;
    int Kend = K;
    if (trapezoid) { int kl = m_base + 256; Kend = kl < K ? kl : K; }
    int kb = 0, ke = Kend;
    if (ksplit) {
        kb = blockIdx.z * ksplit;
        int k2 = kb + ksplit; ke = k2 < Kend ? k2 : Kend;
        if (kb >= ke) return;
        Cb += (size_t)blockIdx.z * M * ldc;
    }
    const int nt = (ke - kb) >> 5;

    // [stage][ A 256x32 (8192 elems) | B 128x32 (4096 elems) ] = 3 x 24 KB
    __shared__ __align__(16) __hip_bfloat16 Lds[3][12288];

    const int tid  = threadIdx.x;
    const int lane = tid & 63;
    const int wave = tid >> 6;
    const int wtm = (wave >> 1) * 128;
    const int wtn = (wave & 1) * 64;

    f32x4 acc[8][4];
#pragma unroll
    for (int i = 0; i < 8; ++i)
#pragma unroll
        for (int j = 0; j < 4; ++j) acc[i][j] = f32x4{0.f, 0.f, 0.f, 0.f};

    const int rsub = lane >> 2;
    const int cx   = (lane & 3) ^ ((lane >> 3) & 3);
    const __hip_bfloat16* GA = A  + (size_t)(m_base + wave * 64) * lda + (size_t)rsub * lda + (size_t)cx * 8 + kb;
    const __hip_bfloat16* GB = Bt + (size_t)(n_base + wave * 32) * ldb + (size_t)rsub * ldb + (size_t)cx * 8 + kb;
    const int ldsA = wave * 2048;
    const int ldsB = 8192 + wave * 1024;

    const int lrow = lane & 15;
    const int cph  = ((lane >> 4) ^ ((lrow >> 1) & 3)) * 8;

#define ISSUE_TILE2(KT, STG)                                                     \
    {                                                                            \
        const size_t ko = (size_t)(KT) * 32;                                     \
        const __hip_bfloat16* ga = GA + ko;                                      \
        __hip_bfloat16* da = &Lds[STG][ldsA];                                    \
        _Pragma("unroll")                                                        \
        for (int q = 0; q < 4; ++q) {                                            \
            __builtin_amdgcn_global_load_lds(AS1P(ga), AS3P(da), 16, 0, 0);      \
            ga += (size_t)16 * lda; da += 512;                                   \
        }                                                                        \
        const __hip_bfloat16* gb = GB + ko;                                      \
        __hip_bfloat16* db = &Lds[STG][ldsB];                                    \
        _Pragma("unroll")                                                        \
        for (int q = 0; q < 2; ++q) {                                            \
            __builtin_amdgcn_global_load_lds(AS1P(gb), AS3P(db), 16, 0, 0);      \
            gb += (size_t)16 * ldb; db += 512;                                   \
        }                                                                        \
    }

    ISSUE_TILE2(0, 0)
    if (nt > 1) ISSUE_TILE2(1, 1)

    int cur = 0;
    for (int kt = 0; kt < nt; ++kt) {
        __builtin_amdgcn_sched_barrier(0);
        if (kt + 1 < nt) __builtin_amdgcn_s_waitcnt(0x0F76);  // vmcnt(6)
        else             __builtin_amdgcn_s_waitcnt(0x0F70);  // vmcnt(0)
        __builtin_amdgcn_sched_barrier(0);
        __builtin_amdgcn_s_barrier();
        __builtin_amdgcn_sched_barrier(0);
        if (kt + 2 < nt) {
            int s2 = cur + 2; if (s2 >= 3) s2 -= 3;
            ISSUE_TILE2(kt + 2, s2)
        }

        bf16x8 af[8], bfv[4];
#pragma unroll
        for (int i = 0; i < 8; ++i)
            af[i] = *(const bf16x8*)&Lds[cur][(wtm + i * 16 + lrow) * 32 + cph];
#pragma unroll
        for (int j = 0; j < 4; ++j)
            bfv[j] = *(const bf16x8*)&Lds[cur][8192 + (wtn + j * 16 + lrow) * 32 + cph];
#pragma unroll
        for (int i = 0; i < 8; ++i)
#pragma unroll
            for (int j = 0; j < 4; ++j)
                acc[i][j] = __builtin_amdgcn_mfma_f32_16x16x32_bf16(af[i], bfv[j], acc[i][j], 0, 0, 0);

        cur = (cur + 1 == 3) ? 0 : cur + 1;
    }
#undef ISSUE_TILE2

    const int r0 = (lane >> 4) * 4;
    const int c0 = lane & 15;
#pragma unroll
    for (int i = 0; i < 8; ++i) {
#pragma unroll
        for (int j = 0; j < 4; ++j) {
            const int col = n_base + wtn + j * 16 + c0;
#pragma unroll
            for (int r = 0; r < 4; ++r) {
                const int row = m_base + wtm + i * 16 + r0 + r;
                float v = acc[i][j][r] * scale;
                if (bias_mode == 1) v += bias[col];
                else if (bias_mode == 2) v += bias[row];
                if (relu) v = fmaxf(v, 0.f);
                Cb[(size_t)row * ldc + col] = __float2bfloat16(v);
            }
        }
    }
}

// ---------------------------------------------------------------------------
// 256x256 bf16 GEMM (big uniform shapes): 8 waves (512 thr) in a 2x4 layout,
// each wave 128x64 out. BK=32, triple-buffer (96KB LDS, 1 block/CU), depth-2
// prefetch, single barrier per iter.
// ---------------------------------------------------------------------------
__global__ __launch_bounds__(512, 2) void gemm_bt3(
    const __hip_bfloat16* __restrict__ A, int lda,
    const __hip_bfloat16* __restrict__ Bt, int ldb,
    int M, int N, int K, int ldc,
    const float* __restrict__ bias, int bias_mode,
    float scale,
    int relu, int causal_skip, int trapezoid, int ksplit,
    __hip_bfloat16* __restrict__ Cb)
{
    int nb = blockIdx.x;
    int mb = blockIdx.y;
    {   // XCD-aware 2D-region swizzle
        const int gx = gridDim.x, gy = gridDim.y;
        if ((gx & 3) == 0 && (gy & 1) == 0) {
            const int id = mb * gx + nb;
            const int X  = id & 7;
            const int L  = id >> 3;
            const int rn = gx >> 2, rm = gy >> 1;
            const int nb_l = L / rm, mb_l = L - nb_l * rm;
            nb = (X & 3) * rn + nb_l;
            mb = (X >> 2) * rm + mb_l;
        }
    }
    const int m_base = mb * 256;
    const int n_base = nb * 256;
    if (causal_skip && (n_base > m_base + 255)) return;
    int Kend = K;
    if (trapezoid) { int kl = m_base + 256; Kend = kl < K ? kl : K; }
    int kb = 0, ke = Kend;
    if (ksplit) {
        kb = blockIdx.z * ksplit;
        int k2 = kb + ksplit; ke = k2 < Kend ? k2 : Kend;
        if (kb >= ke) return;
        Cb += (size_t)blockIdx.z * M * ldc;
    }
    const int nt = (ke - kb) >> 5;

    // [stage][ A 256x32 (8192 elems) | B 256x32 (8192 elems) ] = 3 x 32 KB
    __shared__ __align__(16) __hip_bfloat16 Lds[3][16384];

    const int tid  = threadIdx.x;
    const int lane = tid & 63;
    const int wave = tid >> 6;          // 0..7
    const int wtm = (wave >> 2) * 128;
    const int wtn = (wave & 3) * 64;

    f32x4 acc[8][4];
#pragma unroll
    for (int i = 0; i < 8; ++i)
#pragma unroll
        for (int j = 0; j < 4; ++j) acc[i][j] = f32x4{0.f, 0.f, 0.f, 0.f};

    const int rsub = lane >> 2;
    const int cx   = (lane & 3) ^ ((lane >> 3) & 3);
    const __hip_bfloat16* GA = A  + (size_t)(m_base + wave * 32 + rsub) * lda + (size_t)cx * 8 + kb;
    const __hip_bfloat16* GB = Bt + (size_t)(n_base + wave * 32 + rsub) * ldb + (size_t)cx * 8 + kb;
    const int ldsA = wave * 1024;
    const int ldsB = 8192 + wave * 1024;

    const int lrow = lane & 15;
    const int cph  = ((lane >> 4) ^ ((lrow >> 1) & 3)) * 8;

#define ISSUE_TILE3(KT, STG)                                                     \
    {                                                                            \
        const size_t ko = (size_t)(KT) * 32;                                     \
        const __hip_bfloat16* ga = GA + ko;                                      \
        __hip_bfloat16* da = &Lds[STG][ldsA];                                    \
        _Pragma("unroll")                                                        \
        for (int q = 0; q < 2; ++q) {                                            \
            __builtin_amdgcn_global_load_lds(AS1P(ga), AS3P(da), 16, 0, 0);      \
            ga += (size_t)16 * lda; da += 512;                                   \
        }                                                                        \
        const __hip_bfloat16* gb = GB + ko;                                      \
        __hip_bfloat16* db = &Lds[STG][ldsB];                                    \
        _Pragma("unroll")                                                        \
        for (int q = 0; q < 2; ++q) {                                            \
            __builtin_amdgcn_global_load_lds(AS1P(gb), AS3P(db), 16, 0, 0);      \
            gb += (size_t)16 * ldb; db += 512;                                   \
        }                                                                        \
    }

    ISSUE_TILE3(0, 0)
    if (nt > 1) ISSUE_TILE3(1, 1)

    int cur = 0;
    for (int kt = 0; kt < nt; ++kt) {
        __builtin_amdgcn_sched_barrier(0);
        if (kt + 1 < nt) __builtin_amdgcn_s_waitcnt(0x0F74);  // vmcnt(4)
        else             __builtin_amdgcn_s_waitcnt(0x0F70);  // vmcnt(0)
        __builtin_amdgcn_sched_barrier(0);
        __builtin_amdgcn_s_barrier();
        __builtin_amdgcn_sched_barrier(0);
        if (kt + 2 < nt) {
            int s2 = cur + 2; if (s2 >= 3) s2 -= 3;
            ISSUE_TILE3(kt + 2, s2)
        }

        bf16x8 af[8], bfv[4];
#pragma unroll
        for (int i = 0; i < 8; ++i)
            af[i] = *(const bf16x8*)&Lds[cur][(wtm + i * 16 + lrow) * 32 + cph];
#pragma unroll
        for (int j = 0; j < 4; ++j)
            bfv[j] = *(const bf16x8*)&Lds[cur][8192 + (wtn + j * 16 + lrow) * 32 + cph];
#pragma unroll
        for (int i = 0; i < 8; ++i)
#pragma unroll
            for (int j = 0; j < 4; ++j)
                acc[i][j] = __builtin_amdgcn_mfma_f32_16x16x32_bf16(af[i], bfv[j], acc[i][j], 0, 0, 0);

        cur = (cur + 1 == 3) ? 0 : cur + 1;
    }
#undef ISSUE_TILE3

    const int r0 = (lane >> 4) * 4;
    const int c0 = lane & 15;
#pragma unroll
    for (int i = 0; i < 8; ++i) {
#pragma unroll
        for (int j = 0; j < 4; ++j) {
            const int col = n_base + wtn + j * 16 + c0;
#pragma unroll
            for (int r = 0; r < 4; ++r) {
                const int row = m_base + wtm + i * 16 + r0 + r;
                float v = acc[i][j][r] * scale;
                if (bias_mode == 1) v += bias[col];
                else if (bias_mode == 2) v += bias[row];
                if (relu) v = fmaxf(v, 0.f);
                Cb[(size_t)row * ldc + col] = __float2bfloat16(v);
            }
        }
    }
}

// ---------------------------------------------------------------------------
// Split-K reducer over bf16 partials: C = epi( sum_z Pb[z] )
// ---------------------------------------------------------------------------
__global__ __launch_bounds__(256) void reduce_k_kernel(
    const __hip_bfloat16* __restrict__ Pb, int M, int N, int nsplit, int KC, int trapK,
    const float* __restrict__ bias, const float* __restrict__ residual,
    float* __restrict__ Cf, __hip_bfloat16* __restrict__ Cb)
{
    const int idx = blockIdx.x * 256 + threadIdx.x;
    const int nv = N >> 2;
    const int row = idx / nv;
    if (row >= M) return;
    const int c4 = (idx - row * nv) * 4;
    int nc = nsplit;
    if (trapK) {
        int kend = (row & ~255) + 256; if (kend > trapK) kend = trapK;
        nc = (kend + KC - 1) / KC;
    }
    float s0 = 0.f, s1 = 0.f, s2 = 0.f, s3 = 0.f;
    for (int c = 0; c < nc; ++c) {
        const bf16x4 p = *(const bf16x4*)(Pb + ((size_t)c * M + row) * N + c4);
        s0 += (float)p[0]; s1 += (float)p[1]; s2 += (float)p[2]; s3 += (float)p[3];
    }
    if (bias) {
        const f32x4 b = *(const f32x4*)(bias + c4);
        s0 += b[0]; s1 += b[1]; s2 += b[2]; s3 += b[3];
    }
    if (residual) {
        const f32x4 rv = *(const f32x4*)(residual + (size_t)row * N + c4);
        s0 += rv[0]; s1 += rv[1]; s2 += rv[2]; s3 += rv[3];
    }
    if (Cf) { f32x4 o = {s0, s1, s2, s3}; *(f32x4*)(Cf + (size_t)row * N + c4) = o; }
    else {
        bf16x4 o = { (__bf16)s0, (__bf16)s1, (__bf16)s2, (__bf16)s3 };
        *(bf16x4*)(Cb + (size_t)row * N + c4) = o;
    }
}

// ---------------------------------------------------------------------------
// Fused split-K reduce + bias + residual + row LayerNorm over 1024.
// ---------------------------------------------------------------------------
__global__ __launch_bounds__(256) void reduce_ln_kernel(
    const __hip_bfloat16* __restrict__ Pb, int M, int nsplit,
    const float* __restrict__ bias, const float* __restrict__ residual,
    const float* __restrict__ g, const float* __restrict__ b,
    float* __restrict__ outF, __hip_bfloat16* __restrict__ outB)
{
    __shared__ float sm[8];
    const int row = blockIdx.x;
    const int tid = threadIdx.x;
    const int c4 = tid * 4;

    float v0 = 0.f, v1 = 0.f, v2 = 0.f, v3 = 0.f;
    for (int c = 0; c < nsplit; ++c) {
        const bf16x4 p = *(const bf16x4*)(Pb + ((size_t)c * M + row) * 1024 + c4);
        v0 += (float)p[0]; v1 += (float)p[1]; v2 += (float)p[2]; v3 += (float)p[3];
    }
    {
        const f32x4 bv = *(const f32x4*)(bias + c4);
        v0 += bv[0]; v1 += bv[1]; v2 += bv[2]; v3 += bv[3];
    }
    {
        const f32x4 rv = *(const f32x4*)(residual + (size_t)row * 1024 + c4);
        v0 += rv[0]; v1 += rv[1]; v2 += rv[2]; v3 += rv[3];
    }

    float s  = v0 + v1 + v2 + v3;
    float ss = v0 * v0 + v1 * v1 + v2 * v2 + v3 * v3;
#pragma unroll
    for (int o = 32; o; o >>= 1) { s += __shfl_down(s, o); ss += __shfl_down(ss, o); }
    if ((tid & 63) == 0) { sm[tid >> 6] = s; sm[4 + (tid >> 6)] = ss; }
    __syncthreads();
    s  = sm[0] + sm[1] + sm[2] + sm[3];
    ss = sm[4] + sm[5] + sm[6] + sm[7];
    const float mu   = s * (1.f / 1024.f);
    const float var  = ss * (1.f / 1024.f) - mu * mu;
    const float rstd = rsqrtf(var + 1e-5f);
    const float4 gv = ((const float4*)g)[tid];
    const float4 bv = ((const float4*)b)[tid];
    float4 o;
    o.x = (v0 - mu) * rstd * gv.x + bv.x;
    o.y = (v1 - mu) * rstd * gv.y + bv.y;
    o.z = (v2 - mu) * rstd * gv.z + bv.z;
    o.w = (v3 - mu) * rstd * gv.w + bv.w;
    ((float4*)(outF + (size_t)row * 1024))[tid] = o;
    if (outB) {
        bf16x4 ob = { (__bf16)o.x, (__bf16)o.y, (__bf16)o.z, (__bf16)o.w };
        *(bf16x4*)(outB + (size_t)row * 1024 + c4) = ob;
    }
}

// ---------------------------------------------------------------------------
// Batched prep: all weight transposes (f32 [K,N] -> bf16 [N,K]) and straight
// f32->bf16 converts in ONE dispatch.
// ---------------------------------------------------------------------------
struct PrepTab {
    const float* src[12];
    __hip_bfloat16* dst[12];
    int K[12];
    int N[12];
    int trans[12];
    int blk0[13];
};

__global__ __launch_bounds__(256) void prep_kernel(PrepTab t)
{
    __shared__ float tile[32][33];
    const int bid = blockIdx.x;
    int e = 0;
    while (e < 11 && bid >= t.blk0[e + 1]) ++e;
    const int local = bid - t.blk0[e];
    const int N = t.N[e];
    const int K = t.K[e];
    const int ntx = N >> 5;
    const int n0 = (local % ntx) * 32;
    const int k0 = (local / ntx) * 32;
    const float* __restrict__ W = t.src[e];
    __hip_bfloat16* __restrict__ D = t.dst[e];
    const int tx = threadIdx.x;
    const int ty = threadIdx.y;
    if (t.trans[e]) {
        for (int i = ty; i < 32; i += 8)
            tile[i][tx] = W[(size_t)(k0 + i) * N + n0 + tx];
        __syncthreads();
        for (int i = ty; i < 32; i += 8)
            D[(size_t)(n0 + i) * K + k0 + tx] = __float2bfloat16(tile[tx][i]);
    } else {
        for (int i = ty; i < 32; i += 8) {
            const size_t idx = (size_t)(k0 + i) * N + n0 + tx;
            D[idx] = __float2bfloat16(W[idx]);
        }
    }
}

// ---------------------------------------------------------------------------
// Pack 5 bias vectors (1024 f32 each) into bqkv1[3072] and bkv2[2048].
// ---------------------------------------------------------------------------
__global__ __launch_bounds__(256) void bias_pack_kernel(
    const float* __restrict__ bq1, const float* __restrict__ bk1,
    const float* __restrict__ bv1, const float* __restrict__ bk2,
    const float* __restrict__ bv2, float* __restrict__ bqkv1,
    float* __restrict__ bkv2)
{
    const int i = blockIdx.x * 256 + threadIdx.x;
    if (i < 1024)       bqkv1[i] = bq1[i];
    else if (i < 2048)  bqkv1[i] = bk1[i - 1024];
    else if (i < 3072)  bqkv1[i] = bv1[i - 2048];
    else if (i < 4096)  bkv2[i - 3072] = bk2[i - 3072];
    else if (i < 5120)  bkv2[i - 3072] = bv2[i - 4096];
}

// ---------------------------------------------------------------------------
// Row softmax over bf16 S, single-pass register-resident (N == 4096).
// ---------------------------------------------------------------------------
__global__ __launch_bounds__(256) void softmax_kernel(
    const __hip_bfloat16* __restrict__ S, __hip_bfloat16* __restrict__ A, int N, int causal)
{
    __shared__ float sm[4];
    const int row = blockIdx.x;
    const int tid = threadIdx.x;
    const int limit = causal ? (row + 1) : N;
    const int zl0 = (row & ~255) + 256;
    const int zlimit = causal ? (zl0 < N ? zl0 : N) : N;
    const __hip_bfloat16* Srow = S + (size_t)row * N;
    __hip_bfloat16* Arow = A + (size_t)row * N;

    float x[4][4];
    float m = -3.0e38f;
#pragma unroll
    for (int p = 0; p < 4; ++p) {
        const int cb = p * 1024 + tid * 4;
        if (cb < limit) {
            const bf16x4 xv = *(const bf16x4*)(Srow + cb);
#pragma unroll
            for (int e = 0; e < 4; ++e) {
                const float f = (cb + e < limit) ? (float)xv[e] : -3.0e38f;
                x[p][e] = f;
                m = fmaxf(m, f);
            }
        } else {
#pragma unroll
            for (int e = 0; e < 4; ++e) x[p][e] = -3.0e38f;
        }
    }
#pragma unroll
    for (int o = 32; o; o >>= 1) m = fmaxf(m, __shfl_down(m, o));
    if ((tid & 63) == 0) sm[tid >> 6] = m;
    __syncthreads();
    m = fmaxf(fmaxf(sm[0], sm[1]), fmaxf(sm[2], sm[3]));
    __syncthreads();

    float s = 0.f;
#pragma unroll
    for (int p = 0; p < 4; ++p) {
        const int cb = p * 1024 + tid * 4;
        if (cb < limit) {
#pragma unroll
            for (int e = 0; e < 4; ++e) {
                const float ev = (cb + e < limit) ? __expf(x[p][e] - m) : 0.f;
                x[p][e] = ev;
                s += ev;
            }
        } else {
#pragma unroll
            for (int e = 0; e < 4; ++e) x[p][e] = 0.f;
        }
    }
#pragma unroll
    for (int o = 32; o; o >>= 1) s += __shfl_down(s, o);
    if ((tid & 63) == 0) sm[tid >> 6] = s;
    __syncthreads();
    s = sm[0] + sm[1] + sm[2] + sm[3];
    const float inv = 1.f / s;

#pragma unroll
    for (int p = 0; p < 4; ++p) {
        const int cb = p * 1024 + tid * 4;
        if (cb < zlimit) {
            bf16x4 o = { (__bf16)(x[p][0] * inv), (__bf16)(x[p][1] * inv),
                         (__bf16)(x[p][2] * inv), (__bf16)(x[p][3] * inv) };
            *(bf16x4*)(Arow + cb) = o;
        }
    }
}

// ---------------------------------------------------------------------------
// Launch
// ---------------------------------------------------------------------------
extern "C" void kernel_launch(void* const* d_in, const int* in_sizes, int n_in,
                              void* d_out, int out_size, void* d_ws, size_t ws_size,
                              hipStream_t stream)
{
    const int M = 4096, Pd = 1024, DFF = 4096, NS = 4096;
    const size_t MB = 1024 * 1024;
    const int NOV = 0x40000000;   // "no V-transpose" sentinel column

    const float* Y   = (const float*)d_in[0];
    const float* Xp  = (const float*)d_in[1];
    const float* wq1 = (const float*)d_in[2];  const float* bq1 = (const float*)d_in[3];
    const float* wk1 = (const float*)d_in[4];  const float* bk1 = (const float*)d_in[5];
    const float* wv1 = (const float*)d_in[6];  const float* bv1 = (const float*)d_in[7];
    const float* w0  = (const float*)d_in[8];  const float* b0  = (const float*)d_in[9];
    const float* g1  = (const float*)d_in[10]; const float* be1 = (const float*)d_in[11];
    const float* wq2 = (const float*)d_in[12]; const float* bq2 = (const float*)d_in[13];
    const float* wk2 = (const float*)d_in[14]; const float* bk2 = (const float*)d_in[15];
    const float* wv2 = (const float*)d_in[16]; const float* bv2 = (const float*)d_in[17];
    const float* w1  = (const float*)d_in[18]; const float* b1  = (const float*)d_in[19];
    const float* g2  = (const float*)d_in[20]; const float* be2 = (const float*)d_in[21];
    const float* w2  = (const float*)d_in[22]; const float* b2  = (const float*)d_in[23];
    const float* w3  = (const float*)d_in[24]; const float* b3  = (const float*)d_in[25];
    const float* g3  = (const float*)d_in[26]; const float* be3 = (const float*)d_in[27];

    // ---- workspace layout ----
    char* ws = (char*)d_ws;
    __hip_bfloat16* Ybf   = (__hip_bfloat16*)(ws + 0 * MB);
    __hip_bfloat16* Ubf   = (__hip_bfloat16*)(ws + 0 * MB);
    __hip_bfloat16* Xpbf  = (__hip_bfloat16*)(ws + 8 * MB);
    __hip_bfloat16* AVbf  = (__hip_bfloat16*)(ws + 8 * MB);
    __hip_bfloat16* Qbf   = (__hip_bfloat16*)(ws + 8 * MB);
    __hip_bfloat16* wqkv1t= (__hip_bfloat16*)(ws + 16 * MB);
    __hip_bfloat16* w0t   = (__hip_bfloat16*)(ws + 22 * MB);
    __hip_bfloat16* wq2t  = (__hip_bfloat16*)(ws + 24 * MB);
    __hip_bfloat16* wkv2t = (__hip_bfloat16*)(ws + 26 * MB);
    __hip_bfloat16* w1t   = (__hip_bfloat16*)(ws + 30 * MB);
    __hip_bfloat16* w2t   = (__hip_bfloat16*)(ws + 32 * MB);
    __hip_bfloat16* w3t   = (__hip_bfloat16*)(ws + 40 * MB);
    float*          bqkv1 = (float*)(ws + 48 * MB);
    float*          bkv2  = (float*)(ws + 48 * MB + 512 * 1024);
    __hip_bfloat16* QKV1  = (__hip_bfloat16*)(ws + 49 * MB);
    __hip_bfloat16* KV2   = (__hip_bfloat16*)(ws + 73 * MB);
    __hip_bfloat16* Vt1   = (__hip_bfloat16*)(ws + 89 * MB);   // [Pd, M] bf16 = 8MB
    __hip_bfloat16* Sb    = (__hip_bfloat16*)(ws + 97 * MB);
    __hip_bfloat16* Pb    = (__hip_bfloat16*)(ws + 97 * MB);
    __hip_bfloat16* Abf   = (__hip_bfloat16*)(ws + 161 * MB);
    __hip_bfloat16* Vt2   = (__hip_bfloat16*)(ws + 193 * MB);  // [Pd, NS] bf16 = 8MB
    float*          Uf    = (float*)(ws + 209 * MB);
    float*          Out   = (float*)d_out;
    if (ws_size < 225 * MB) return;

    auto gemm = [&](const __hip_bfloat16* A, int lda, const __hip_bfloat16* Bt, int ldb,
                    int Mm, int Nn, int Kk, int ldc,
                    const float* bias, int bmode, float scale, const float* res,
                    int relu, int causal, int trap, int ksplit,
                    float* Cf, __hip_bfloat16* Cb) {
        const int nz = ksplit ? (Kk + ksplit - 1) / ksplit : 1;
        gemm_bt<<<dim3(Nn / 128, Mm / 128, nz), dim3(256), 0, stream>>>(
            A, lda, Bt, ldb, Mm, Nn, Kk, ldc, bias, bmode, scale, res, relu, causal, trap, ksplit,
            Cf, Cb, NOV, nullptr, 0,
            0, nullptr, nullptr, 0, 0, nullptr, nullptr, NOV, nullptr, 0);
    };
    auto gemm2 = [&](const __hip_bfloat16* A, int lda, const __hip_bfloat16* Bt, int ldb,
                     int Mm, int Nn, int Kk, int ldc,
                     const float* bias, int bmode, float scale,
                     int relu, int causal, int trap, int ksplit, __hip_bfloat16* Cb) {
        const int nz = ksplit ? (Kk + ksplit - 1) / ksplit : 1;
        gemm_bt2<<<dim3(Nn / 128, Mm / 256, nz), dim3(256), 0, stream>>>(
            A, lda, Bt, ldb, Mm, Nn, Kk, ldc, bias, bmode, scale, relu, causal, trap, ksplit, Cb);
    };
    auto gemm3 = [&](const __hip_bfloat16* A, int lda, const __hip_bfloat16* Bt, int ldb,
                     int Mm, int Nn, int Kk, int ldc,
                     const float* bias, int bmode, float scale,
                     int relu, int causal, int trap, int ksplit, __hip_bfloat16* Cb) {
        const int nz = ksplit ? (Kk + ksplit - 1) / ksplit : 1;
        gemm_bt3<<<dim3(Nn / 256, Mm / 256, nz), dim3(512), 0, stream>>>(
            A, lda, Bt, ldb, Mm, Nn, Kk, ldc, bias, bmode, scale, relu, causal, trap, ksplit, Cb);
    };
    auto reduce = [&](const __hip_bfloat16* P, int Mm, int Nn, int nsplit, int KC, int trapK,
                      const float* bias, const float* res, float* Cf, __hip_bfloat16* Cb) {
        reduce_k_kernel<<<dim3(Mm * Nn / 1024), dim3(256), 0, stream>>>(
            P, Mm, Nn, nsplit, KC, trapK, bias, res, Cf, Cb);
    };
    auto reduce_ln = [&](const __hip_bfloat16* P, int nsplit,
                         const float* bias, const float* res,
                         const float* gg, const float* bb,
                         float* outF, __hip_bfloat16* outB) {
        reduce_ln_kernel<<<dim3(M), dim3(256), 0, stream>>>(
            P, M, nsplit, bias, res, gg, bb, outF, outB);
    };

    const float scl = 0.03125f;  // 1/sqrt(1024)

    // --- prep: one batched dispatch for all transposes + converts ---
    {
        PrepTab t;
        const float* srcs[12]  = { wq1, wk1, wv1, w0, wq2, wk2, wv2, w1, w2, w3, Y, Xp };
        __hip_bfloat16* dsts[12] = { wqkv1t, wqkv1t + Pd * Pd, wqkv1t + 2 * Pd * Pd,
                                     w0t, wq2t, wkv2t, wkv2t + Pd * Pd, w1t,
                                     w2t, w3t, Ybf, Xpbf };
        const int Ks[12] = { Pd, Pd, Pd, Pd, Pd, Pd, Pd, Pd, Pd,  DFF, M,  NS };
        const int Ns[12] = { Pd, Pd, Pd, Pd, Pd, Pd, Pd, Pd, DFF, Pd,  Pd, Pd };
        const int trs[12] = { 1, 1, 1, 1, 1, 1, 1, 1, 1, 1, 0, 0 };
        int acc = 0;
        for (int e = 0; e < 12; ++e) {
            t.src[e] = srcs[e]; t.dst[e] = dsts[e];
            t.K[e] = Ks[e]; t.N[e] = Ns[e]; t.trans[e] = trs[e];
            t.blk0[e] = acc;
            acc += (Ns[e] / 32) * (Ks[e] / 32);
        }
        t.blk0[12] = acc;
        prep_kernel<<<dim3(acc), dim3(32, 8), 0, stream>>>(t);
    }
    bias_pack_kernel<<<dim3(20), dim3(256), 0, stream>>>(bq1, bk1, bv1, bk2, bv2, bqkv1, bkv2);

    // --- merged projections: QKV1 (24 n-blocks) + KV2 (16 n-blocks), 128-tile.
    //     V columns written transposed directly into Vt1 / Vt2. ---
    gemm_bt<<<dim3(40, 32, 1), dim3(256), 0, stream>>>(
        Ybf, Pd, wqkv1t, Pd, M, 3072, Pd, 3072, bqkv1, 1, 1.f, nullptr, 0, 0, 0, 0,
        nullptr, QKV1, 2048, Vt1, M,
        24, Xpbf, wkv2t, Pd, 2048, bkv2, KV2, 1024, Vt2, NS);

    // --- masked self-attention (ragged shapes stay on 256x128 kernel) ---
    gemm2(QKV1, 3072, QKV1 + 1024, 3072, M, M, Pd, M,
          nullptr, 0, scl, 0, 1, 0, 0, Sb);                      // causal S1
    softmax_kernel<<<dim3(M), dim3(256), 0, stream>>>(Sb, Abf, M, 1);
    gemm2(Abf, M, Vt1, M, M, Pd, M, Pd,
          nullptr, 0, 1.f, 0, 0, 1, 1024, Pb);                   // AV1 trapezoid splitK=4
    reduce(Pb, M, Pd, 4, 1024, M, nullptr, nullptr, nullptr, AVbf);
    gemm(AVbf, Pd, w0t, Pd, M, Pd, Pd, Pd,
         nullptr, 0, 1.f, nullptr, 0, 0, 0, 512, nullptr, Pb);   // w0 splitK=2
    reduce_ln(Pb, 2, b0, Y, g1, be1, Uf, Ubf);                   // + residual Y + LN1

    // --- cross-attention (uniform big shapes on 256x256 kernel) ---
    gemm(Ubf, Pd, wq2t, Pd, M, Pd, Pd, Pd,
         nullptr, 0, 1.f, nullptr, 0, 0, 0, 512, nullptr, Pb);   // wq2 splitK=2
    reduce(Pb, M, Pd, 2, 512, 0, bq2, nullptr, nullptr, Qbf);
    gemm3(Qbf, Pd, KV2, 2048, M, NS, Pd, NS,
          nullptr, 0, scl, 0, 0, 0, 0, Sb);                      // S2 (256x256, 16x16 grid)
    softmax_kernel<<<dim3(M), dim3(256), 0, stream>>>(Sb, Abf, NS, 0);
    gemm3(Abf, NS, Vt2, NS, M, Pd, NS, Pd,
          nullptr, 0, 1.f, 0, 0, 0, 1024, Pb);                   // AV2 splitK=4 (4x16x4)
    reduce(Pb, M, Pd, 4, 1024, 0, nullptr, nullptr, nullptr, AVbf);
    gemm(AVbf, Pd, w1t, Pd, M, Pd, Pd, Pd,
         nullptr, 0, 1.f, nullptr, 0, 0, 0, 512, nullptr, Pb);   // w1 splitK=2
    reduce_ln(Pb, 2, b1, Uf, g2, be2, Uf, Ubf);                  // + residual U1 + LN2

    // --- FFN (uniform big shapes on 256x256 kernel) ---
    gemm3(Ubf, Pd, w2t, Pd, M, DFF, Pd, DFF, b2, 1, 1.f, 1, 0, 0, 0, Abf);  // FFN1 relu (16x16)
    gemm3(Abf, DFF, w3t, DFF, M, Pd, DFF, Pd,
          nullptr, 0, 1.f, 0, 0, 0, 1024, Pb);                   // FFN2 splitK=4 (4x16x4)
    reduce_ln(Pb, 4, b3, Uf, g3, be3, Out, nullptr);             // + residual U2 + LN3
}

// Round 7
// 668.304 us; speedup vs baseline: 1.1013x; 1.1013x over previous
//
#include <hip/hip_runtime.h>
#include <hip/hip_bf16.h>

typedef __bf16 bf16x8 __attribute__((ext_vector_type(8)));
typedef __bf16 bf16x4 __attribute__((ext_vector_type(4)));
typedef float f32x4 __attribute__((ext_vector_type(4)));

#define AS1P(p) ((__attribute__((address_space(1))) void*)(void*)(p))
#define AS3P(p) ((__attribute__((address_space(3))) void*)(p))

// ---------------------------------------------------------------------------
// 128x128 bf16 GEMM (projections / thin-N): BK=32 triple-buffer, depth-2
// prefetch, single-barrier K-loop, XOR-swizzled LDS (conflict-free), XCD
// region swizzle. 48KB LDS -> 3 blocks/CU.
// MEASURED LOCAL OPTIMUM (76.5us projection). Round-6 lesson: depth-2
// prefetch with counted vmcnt is load-bearing — a 2-phase double-buffer
// variant (5 blocks/CU attempt) collapsed to 150us+ (exposed HBM latency
// per K-step; achieved residency only ~2.4 blocks/CU). Do not shallow it.
// V-columns (col >= vcol0) are written TRANSPOSED to Vt ([P, M] layout).
// ---------------------------------------------------------------------------
__global__ __launch_bounds__(256, 3) void gemm_bt(
    const __hip_bfloat16* __restrict__ A, int lda,
    const __hip_bfloat16* __restrict__ Bt, int ldb,
    int M, int N, int K, int ldc,
    const float* __restrict__ bias, int bias_mode,   // 0 none, 1 per-col, 2 per-row
    float scale,
    const float* __restrict__ residual,              // f32 [M,ldc] or null
    int relu, int causal_skip, int trapezoid, int ksplit,
    float* __restrict__ Cf, __hip_bfloat16* __restrict__ Cb,
    int vcol0, __hip_bfloat16* __restrict__ Vt, int ldvt,
    // fused second GEMM (blocks with nb >= nsplit1); shares lda/M/K
    int nsplit1, const __hip_bfloat16* __restrict__ A2,
    const __hip_bfloat16* __restrict__ Bt2, int ldb2, int ldc2,
    const float* __restrict__ bias2, __hip_bfloat16* __restrict__ Cb2,
    int vcol0_2, __hip_bfloat16* __restrict__ Vt2, int ldvt2)
{
    int nb = blockIdx.x;
    int mb = blockIdx.y;
    {   // XCD-aware 2D-region swizzle (identity if shape not divisible)
        const int gx = gridDim.x, gy = gridDim.y;
        if ((gx & 3) == 0 && (gy & 1) == 0) {
            const int id = mb * gx + nb;
            const int X  = id & 7;
            const int L  = id >> 3;
            const int rn = gx >> 2, rm = gy >> 1;
            const int nb_l = L / rm, mb_l = L - nb_l * rm;
            nb = (X & 3) * rn + nb_l;
            mb = (X >> 2) * rm + mb_l;
        }
    }
    if (nsplit1 && nb >= nsplit1) {
        A = A2; Bt = Bt2; ldb = ldb2; ldc = ldc2; bias = bias2;
        Cb = Cb2; Cf = nullptr; residual = nullptr;
        vcol0 = vcol0_2; Vt = Vt2; ldvt = ldvt2;
        nb -= nsplit1;
    }
    const int m_base = mb * 128;
    const int n_base = nb * 128;
    if (causal_skip && (n_base > m_base + 127)) return;
    int Kend = K;
    if (trapezoid) { int kl = m_base + 128; Kend = kl < K ? kl : K; }
    int kb = 0, ke = Kend;
    if (ksplit) {
        kb = blockIdx.z * ksplit;
        int k2 = kb + ksplit; ke = k2 < Kend ? k2 : Kend;
        if (kb >= ke) return;
        Cb += (size_t)blockIdx.z * M * ldc;
        Cf = nullptr;
    }
    const int nt = (ke - kb) >> 5;

    __shared__ __align__(16) __hip_bfloat16 Lds[3][8192];

    const int tid  = threadIdx.x;
    const int lane = tid & 63;
    const int wave = tid >> 6;
    const int wm = (wave >> 1) * 64;
    const int wn = (wave & 1) * 64;

    f32x4 acc[4][4];
#pragma unroll
    for (int i = 0; i < 4; ++i)
#pragma unroll
        for (int j = 0; j < 4; ++j) acc[i][j] = f32x4{0.f, 0.f, 0.f, 0.f};

    const bool isA = wave < 2;
    const __hip_bfloat16* G = isA ? (A + (size_t)m_base * lda) : (Bt + (size_t)n_base * ldb);
    const int ldg = isA ? lda : ldb;
    const int q0 = (wave & 1) * 4;
    const int rsub = lane >> 2;
    const int cx   = (lane & 3) ^ ((lane >> 3) & 3);
    const size_t grow = (size_t)(q0 * 16 + rsub) * ldg + (size_t)cx * 8 + kb;
    const int ldsoff = (isA ? 0 : 4096) + q0 * 512;

    const int lrow = lane & 15;
    const int cph  = ((lane >> 4) ^ ((lrow >> 1) & 3)) * 8;

#define ISSUE_TILE(KT, STG)                                                      \
    {                                                                            \
        const __hip_bfloat16* g = G + grow + (size_t)(KT) * 32;                  \
        __hip_bfloat16* dst = &Lds[STG][ldsoff];                                 \
        _Pragma("unroll")                                                        \
        for (int q = 0; q < 4; ++q) {                                            \
            __builtin_amdgcn_global_load_lds(AS1P(g), AS3P(dst), 16, 0, 0);      \
            g += (size_t)16 * ldg; dst += 512;                                   \
        }                                                                        \
    }

    ISSUE_TILE(0, 0)
    if (nt > 1) ISSUE_TILE(1, 1)

    int cur = 0;
    for (int kt = 0; kt < nt; ++kt) {
        __builtin_amdgcn_sched_barrier(0);
        if (kt + 1 < nt) __builtin_amdgcn_s_waitcnt(0x0F74);  // vmcnt(4)
        else             __builtin_amdgcn_s_waitcnt(0x0F70);  // vmcnt(0)
        __builtin_amdgcn_sched_barrier(0);
        __builtin_amdgcn_s_barrier();
        __builtin_amdgcn_sched_barrier(0);
        if (kt + 2 < nt) {
            int s2 = cur + 2; if (s2 >= 3) s2 -= 3;
            ISSUE_TILE(kt + 2, s2)
        }

        bf16x8 af[4], bfv[4];
#pragma unroll
        for (int i = 0; i < 4; ++i)
            af[i] = *(const bf16x8*)&Lds[cur][(wm + i * 16 + lrow) * 32 + cph];
#pragma unroll
        for (int j = 0; j < 4; ++j)
            bfv[j] = *(const bf16x8*)&Lds[cur][4096 + (wn + j * 16 + lrow) * 32 + cph];
#pragma unroll
        for (int i = 0; i < 4; ++i)
#pragma unroll
            for (int j = 0; j < 4; ++j)
                acc[i][j] = __builtin_amdgcn_mfma_f32_16x16x32_bf16(af[i], bfv[j], acc[i][j], 0, 0, 0);

        cur = (cur + 1 == 3) ? 0 : cur + 1;
    }
#undef ISSUE_TILE

    const int r0 = (lane >> 4) * 4;
    const int c0 = lane & 15;
    const bool vtrans = (n_base >= vcol0);   // vcol0 multiple of 128 -> block-uniform
#pragma unroll
    for (int i = 0; i < 4; ++i) {
#pragma unroll
        for (int j = 0; j < 4; ++j) {
            const int col = n_base + wn + j * 16 + c0;
            const int row0 = m_base + wm + i * 16 + r0;
            float vv[4];
#pragma unroll
            for (int r = 0; r < 4; ++r) {
                float v = acc[i][j][r] * scale;
                if (bias_mode == 1) v += bias[col];
                else if (bias_mode == 2) v += bias[row0 + r];
                if (relu) v = fmaxf(v, 0.f);
                vv[r] = v;
            }
            if (vtrans) {
                bf16x4 o = { (__bf16)vv[0], (__bf16)vv[1], (__bf16)vv[2], (__bf16)vv[3] };
                *(bf16x4*)(Vt + (size_t)(col - vcol0) * ldvt + row0) = o;
            } else {
#pragma unroll
                for (int r = 0; r < 4; ++r) {
                    const size_t idx = (size_t)(row0 + r) * ldc + col;
                    float v = vv[r];
                    if (residual) v += residual[idx];
                    if (Cf) Cf[idx] = v;
                    else    Cb[idx] = __float2bfloat16(v);
                }
            }
        }
    }
}

// ---------------------------------------------------------------------------
// 256x128 bf16 GEMM: 4 waves each 128x64, BK=32 triple-buffer (72KB LDS,
// 2 blocks/CU), depth-2 prefetch, single barrier per iter. Used for the
// ragged attention shapes (causal S1 / trapezoid AV1).
// ---------------------------------------------------------------------------
__global__ __launch_bounds__(256, 2) void gemm_bt2(
    const __hip_bfloat16* __restrict__ A, int lda,
    const __hip_bfloat16* __restrict__ Bt, int ldb,
    int M, int N, int K, int ldc,
    const float* __restrict__ bias, int bias_mode,
    float scale,
    int relu, int causal_skip, int trapezoid, int ksplit,
    __hip_bfloat16* __restrict__ Cb)
{
    int nb = blockIdx.x;
    int mb = blockIdx.y;
    {   // XCD-aware 2D-region swizzle
        const int gx = gridDim.x, gy = gridDim.y;
        if ((gx & 3) == 0 && (gy & 1) == 0) {
            const int id = mb * gx + nb;
            const int X  = id & 7;
            const int L  = id >> 3;
            const int rn = gx >> 2, rm = gy >> 1;
            const int nb_l = L / rm, mb_l = L - nb_l * rm;
            nb = (X & 3) * rn + nb_l;
            mb = (X >> 2) * rm + mb_l;
        }
    }
    const int m_base = mb * 256;
    const int n_base = nb * 128;
    if (causal_skip && (n_base > m_base + 255)) return;
    int Kend = K;
    if (trapezoid) { int kl = m_base + 256; Kend = kl < K ? kl : K; }
    int kb = 0, ke = Kend;
    if (ksplit) {
        kb = blockIdx.z * ksplit;
        int k2 = kb + ksplit; ke = k2 < Kend ? k2 : Kend;
        if (kb >= ke) return;
        Cb += (size_t)blockIdx.z * M * ldc;
    }
    const int nt = (ke - kb) >> 5;

    // [stage][ A 256x32 (8192 elems) | B 128x32 (4096 elems) ] = 3 x 24 KB
    __shared__ __align__(16) __hip_bfloat16 Lds[3][12288];

    const int tid  = threadIdx.x;
    const int lane = tid & 63;
    const int wave = tid >> 6;
    const int wtm = (wave >> 1) * 128;
    const int wtn = (wave & 1) * 64;

    f32x4 acc[8][4];
#pragma unroll
    for (int i = 0; i < 8; ++i)
#pragma unroll
        for (int j = 0; j < 4; ++j) acc[i][j] = f32x4{0.f, 0.f, 0.f, 0.f};

    const int rsub = lane >> 2;
    const int cx   = (lane & 3) ^ ((lane >> 3) & 3);
    const __hip_bfloat16* GA = A  + (size_t)(m_base + wave * 64) * lda + (size_t)rsub * lda + (size_t)cx * 8 + kb;
    const __hip_bfloat16* GB = Bt + (size_t)(n_base + wave * 32) * ldb + (size_t)rsub * ldb + (size_t)cx * 8 + kb;
    const int ldsA = wave * 2048;
    const int ldsB = 8192 + wave * 1024;

    const int lrow = lane & 15;
    const int cph  = ((lane >> 4) ^ ((lrow >> 1) & 3)) * 8;

#define ISSUE_TILE2(KT, STG)                                                     \
    {                                                                            \
        const size_t ko = (size_t)(KT) * 32;                                     \
        const __hip_bfloat16* ga = GA + ko;                                      \
        __hip_bfloat16* da = &Lds[STG][ldsA];                                    \
        _Pragma("unroll")                                                        \
        for (int q = 0; q < 4; ++q) {                                            \
            __builtin_amdgcn_global_load_lds(AS1P(ga), AS3P(da), 16, 0, 0);      \
            ga += (size_t)16 * lda; da += 512;                                   \
        }                                                                        \
        const __hip_bfloat16* gb = GB + ko;                                      \
        __hip_bfloat16* db = &Lds[STG][ldsB];                                    \
        _Pragma("unroll")                                                        \
        for (int q = 0; q < 2; ++q) {                                            \
            __builtin_amdgcn_global_load_lds(AS1P(gb), AS3P(db), 16, 0, 0);      \
            gb += (size_t)16 * ldb; db += 512;                                   \
        }                                                                        \
    }

    ISSUE_TILE2(0, 0)
    if (nt > 1) ISSUE_TILE2(1, 1)

    int cur = 0;
    for (int kt = 0; kt < nt; ++kt) {
        __builtin_amdgcn_sched_barrier(0);
        if (kt + 1 < nt) __builtin_amdgcn_s_waitcnt(0x0F76);  // vmcnt(6)
        else             __builtin_amdgcn_s_waitcnt(0x0F70);  // vmcnt(0)
        __builtin_amdgcn_sched_barrier(0);
        __builtin_amdgcn_s_barrier();
        __builtin_amdgcn_sched_barrier(0);
        if (kt + 2 < nt) {
            int s2 = cur + 2; if (s2 >= 3) s2 -= 3;
            ISSUE_TILE2(kt + 2, s2)
        }

        bf16x8 af[8], bfv[4];
#pragma unroll
        for (int i = 0; i < 8; ++i)
            af[i] = *(const bf16x8*)&Lds[cur][(wtm + i * 16 + lrow) * 32 + cph];
#pragma unroll
        for (int j = 0; j < 4; ++j)
            bfv[j] = *(const bf16x8*)&Lds[cur][8192 + (wtn + j * 16 + lrow) * 32 + cph];
#pragma unroll
        for (int i = 0; i < 8; ++i)
#pragma unroll
            for (int j = 0; j < 4; ++j)
                acc[i][j] = __builtin_amdgcn_mfma_f32_16x16x32_bf16(af[i], bfv[j], acc[i][j], 0, 0, 0);

        cur = (cur + 1 == 3) ? 0 : cur + 1;
    }
#undef ISSUE_TILE2

    const int r0 = (lane >> 4) * 4;
    const int c0 = lane & 15;
#pragma unroll
    for (int i = 0; i < 8; ++i) {
#pragma unroll
        for (int j = 0; j < 4; ++j) {
            const int col = n_base + wtn + j * 16 + c0;
#pragma unroll
            for (int r = 0; r < 4; ++r) {
                const int row = m_base + wtm + i * 16 + r0 + r;
                float v = acc[i][j][r] * scale;
                if (bias_mode == 1) v += bias[col];
                else if (bias_mode == 2) v += bias[row];
                if (relu) v = fmaxf(v, 0.f);
                Cb[(size_t)row * ldc + col] = __float2bfloat16(v);
            }
        }
    }
}

// ---------------------------------------------------------------------------
// 256x256 bf16 GEMM (big uniform shapes): 8 waves (512 thr) in a 2x4 layout,
// each wave 128x64 out. BK=32, triple-buffer (96KB LDS, 1 block/CU), depth-2
// prefetch, single barrier per iter.
// ---------------------------------------------------------------------------
__global__ __launch_bounds__(512, 2) void gemm_bt3(
    const __hip_bfloat16* __restrict__ A, int lda,
    const __hip_bfloat16* __restrict__ Bt, int ldb,
    int M, int N, int K, int ldc,
    const float* __restrict__ bias, int bias_mode,
    float scale,
    int relu, int causal_skip, int trapezoid, int ksplit,
    __hip_bfloat16* __restrict__ Cb)
{
    int nb = blockIdx.x;
    int mb = blockIdx.y;
    {   // XCD-aware 2D-region swizzle
        const int gx = gridDim.x, gy = gridDim.y;
        if ((gx & 3) == 0 && (gy & 1) == 0) {
            const int id = mb * gx + nb;
            const int X  = id & 7;
            const int L  = id >> 3;
            const int rn = gx >> 2, rm = gy >> 1;
            const int nb_l = L / rm, mb_l = L - nb_l * rm;
            nb = (X & 3) * rn + nb_l;
            mb = (X >> 2) * rm + mb_l;
        }
    }
    const int m_base = mb * 256;
    const int n_base = nb * 256;
    if (causal_skip && (n_base > m_base + 255)) return;
    int Kend = K;
    if (trapezoid) { int kl = m_base + 256; Kend = kl < K ? kl : K; }
    int kb = 0, ke = Kend;
    if (ksplit) {
        kb = blockIdx.z * ksplit;
        int k2 = kb + ksplit; ke = k2 < Kend ? k2 : Kend;
        if (kb >= ke) return;
        Cb += (size_t)blockIdx.z * M * ldc;
    }
    const int nt = (ke - kb) >> 5;

    // [stage][ A 256x32 (8192 elems) | B 256x32 (8192 elems) ] = 3 x 32 KB
    __shared__ __align__(16) __hip_bfloat16 Lds[3][16384];

    const int tid  = threadIdx.x;
    const int lane = tid & 63;
    const int wave = tid >> 6;          // 0..7
    const int wtm = (wave >> 2) * 128;
    const int wtn = (wave & 3) * 64;

    f32x4 acc[8][4];
#pragma unroll
    for (int i = 0; i < 8; ++i)
#pragma unroll
        for (int j = 0; j < 4; ++j) acc[i][j] = f32x4{0.f, 0.f, 0.f, 0.f};

    const int rsub = lane >> 2;
    const int cx   = (lane & 3) ^ ((lane >> 3) & 3);
    const __hip_bfloat16* GA = A  + (size_t)(m_base + wave * 32 + rsub) * lda + (size_t)cx * 8 + kb;
    const __hip_bfloat16* GB = Bt + (size_t)(n_base + wave * 32 + rsub) * ldb + (size_t)cx * 8 + kb;
    const int ldsA = wave * 1024;
    const int ldsB = 8192 + wave * 1024;

    const int lrow = lane & 15;
    const int cph  = ((lane >> 4) ^ ((lrow >> 1) & 3)) * 8;

#define ISSUE_TILE3(KT, STG)                                                     \
    {                                                                            \
        const size_t ko = (size_t)(KT) * 32;                                     \
        const __hip_bfloat16* ga = GA + ko;                                      \
        __hip_bfloat16* da = &Lds[STG][ldsA];                                    \
        _Pragma("unroll")                                                        \
        for (int q = 0; q < 2; ++q) {                                            \
            __builtin_amdgcn_global_load_lds(AS1P(ga), AS3P(da), 16, 0, 0);      \
            ga += (size_t)16 * lda; da += 512;                                   \
        }                                                                        \
        const __hip_bfloat16* gb = GB + ko;                                      \
        __hip_bfloat16* db = &Lds[STG][ldsB];                                    \
        _Pragma("unroll")                                                        \
        for (int q = 0; q < 2; ++q) {                                            \
            __builtin_amdgcn_global_load_lds(AS1P(gb), AS3P(db), 16, 0, 0);      \
            gb += (size_t)16 * ldb; db += 512;                                   \
        }                                                                        \
    }

    ISSUE_TILE3(0, 0)
    if (nt > 1) ISSUE_TILE3(1, 1)

    int cur = 0;
    for (int kt = 0; kt < nt; ++kt) {
        __builtin_amdgcn_sched_barrier(0);
        if (kt + 1 < nt) __builtin_amdgcn_s_waitcnt(0x0F74);  // vmcnt(4)
        else             __builtin_amdgcn_s_waitcnt(0x0F70);  // vmcnt(0)
        __builtin_amdgcn_sched_barrier(0);
        __builtin_amdgcn_s_barrier();
        __builtin_amdgcn_sched_barrier(0);
        if (kt + 2 < nt) {
            int s2 = cur + 2; if (s2 >= 3) s2 -= 3;
            ISSUE_TILE3(kt + 2, s2)
        }

        bf16x8 af[8], bfv[4];
#pragma unroll
        for (int i = 0; i < 8; ++i)
            af[i] = *(const bf16x8*)&Lds[cur][(wtm + i * 16 + lrow) * 32 + cph];
#pragma unroll
        for (int j = 0; j < 4; ++j)
            bfv[j] = *(const bf16x8*)&Lds[cur][8192 + (wtn + j * 16 + lrow) * 32 + cph];
#pragma unroll
        for (int i = 0; i < 8; ++i)
#pragma unroll
            for (int j = 0; j < 4; ++j)
                acc[i][j] = __builtin_amdgcn_mfma_f32_16x16x32_bf16(af[i], bfv[j], acc[i][j], 0, 0, 0);

        cur = (cur + 1 == 3) ? 0 : cur + 1;
    }
#undef ISSUE_TILE3

    const int r0 = (lane >> 4) * 4;
    const int c0 = lane & 15;
#pragma unroll
    for (int i = 0; i < 8; ++i) {
#pragma unroll
        for (int j = 0; j < 4; ++j) {
            const int col = n_base + wtn + j * 16 + c0;
#pragma unroll
            for (int r = 0; r < 4; ++r) {
                const int row = m_base + wtm + i * 16 + r0 + r;
                float v = acc[i][j][r] * scale;
                if (bias_mode == 1) v += bias[col];
                else if (bias_mode == 2) v += bias[row];
                if (relu) v = fmaxf(v, 0.f);
                Cb[(size_t)row * ldc + col] = __float2bfloat16(v);
            }
        }
    }
}

// ---------------------------------------------------------------------------
// Split-K reducer over bf16 partials: C = epi( sum_z Pb[z] )
// ---------------------------------------------------------------------------
__global__ __launch_bounds__(256) void reduce_k_kernel(
    const __hip_bfloat16* __restrict__ Pb, int M, int N, int nsplit, int KC, int trapK,
    const float* __restrict__ bias, const float* __restrict__ residual,
    float* __restrict__ Cf, __hip_bfloat16* __restrict__ Cb)
{
    const int idx = blockIdx.x * 256 + threadIdx.x;
    const int nv = N >> 2;
    const int row = idx / nv;
    if (row >= M) return;
    const int c4 = (idx - row * nv) * 4;
    int nc = nsplit;
    if (trapK) {
        int kend = (row & ~255) + 256; if (kend > trapK) kend = trapK;
        nc = (kend + KC - 1) / KC;
    }
    float s0 = 0.f, s1 = 0.f, s2 = 0.f, s3 = 0.f;
    for (int c = 0; c < nc; ++c) {
        const bf16x4 p = *(const bf16x4*)(Pb + ((size_t)c * M + row) * N + c4);
        s0 += (float)p[0]; s1 += (float)p[1]; s2 += (float)p[2]; s3 += (float)p[3];
    }
    if (bias) {
        const f32x4 b = *(const f32x4*)(bias + c4);
        s0 += b[0]; s1 += b[1]; s2 += b[2]; s3 += b[3];
    }
    if (residual) {
        const f32x4 rv = *(const f32x4*)(residual + (size_t)row * N + c4);
        s0 += rv[0]; s1 += rv[1]; s2 += rv[2]; s3 += rv[3];
    }
    if (Cf) { f32x4 o = {s0, s1, s2, s3}; *(f32x4*)(Cf + (size_t)row * N + c4) = o; }
    else {
        bf16x4 o = { (__bf16)s0, (__bf16)s1, (__bf16)s2, (__bf16)s3 };
        *(bf16x4*)(Cb + (size_t)row * N + c4) = o;
    }
}

// ---------------------------------------------------------------------------
// Fused split-K reduce + bias + residual + row LayerNorm over 1024.
// ---------------------------------------------------------------------------
__global__ __launch_bounds__(256) void reduce_ln_kernel(
    const __hip_bfloat16* __restrict__ Pb, int M, int nsplit,
    const float* __restrict__ bias, const float* __restrict__ residual,
    const float* __restrict__ g, const float* __restrict__ b,
    float* __restrict__ outF, __hip_bfloat16* __restrict__ outB)
{
    __shared__ float sm[8];
    const int row = blockIdx.x;
    const int tid = threadIdx.x;
    const int c4 = tid * 4;

    float v0 = 0.f, v1 = 0.f, v2 = 0.f, v3 = 0.f;
    for (int c = 0; c < nsplit; ++c) {
        const bf16x4 p = *(const bf16x4*)(Pb + ((size_t)c * M + row) * 1024 + c4);
        v0 += (float)p[0]; v1 += (float)p[1]; v2 += (float)p[2]; v3 += (float)p[3];
    }
    {
        const f32x4 bv = *(const f32x4*)(bias + c4);
        v0 += bv[0]; v1 += bv[1]; v2 += bv[2]; v3 += bv[3];
    }
    {
        const f32x4 rv = *(const f32x4*)(residual + (size_t)row * 1024 + c4);
        v0 += rv[0]; v1 += rv[1]; v2 += rv[2]; v3 += rv[3];
    }

    float s  = v0 + v1 + v2 + v3;
    float ss = v0 * v0 + v1 * v1 + v2 * v2 + v3 * v3;
#pragma unroll
    for (int o = 32; o; o >>= 1) { s += __shfl_down(s, o); ss += __shfl_down(ss, o); }
    if ((tid & 63) == 0) { sm[tid >> 6] = s; sm[4 + (tid >> 6)] = ss; }
    __syncthreads();
    s  = sm[0] + sm[1] + sm[2] + sm[3];
    ss = sm[4] + sm[5] + sm[6] + sm[7];
    const float mu   = s * (1.f / 1024.f);
    const float var  = ss * (1.f / 1024.f) - mu * mu;
    const float rstd = rsqrtf(var + 1e-5f);
    const float4 gv = ((const float4*)g)[tid];
    const float4 bv = ((const float4*)b)[tid];
    float4 o;
    o.x = (v0 - mu) * rstd * gv.x + bv.x;
    o.y = (v1 - mu) * rstd * gv.y + bv.y;
    o.z = (v2 - mu) * rstd * gv.z + bv.z;
    o.w = (v3 - mu) * rstd * gv.w + bv.w;
    ((float4*)(outF + (size_t)row * 1024))[tid] = o;
    if (outB) {
        bf16x4 ob = { (__bf16)o.x, (__bf16)o.y, (__bf16)o.z, (__bf16)o.w };
        *(bf16x4*)(outB + (size_t)row * 1024 + c4) = ob;
    }
}

// ---------------------------------------------------------------------------
// Batched prep: all weight transposes (f32 [K,N] -> bf16 [N,K]) and straight
// f32->bf16 converts in ONE dispatch.
// ---------------------------------------------------------------------------
struct PrepTab {
    const float* src[12];
    __hip_bfloat16* dst[12];
    int K[12];
    int N[12];
    int trans[12];
    int blk0[13];
};

__global__ __launch_bounds__(256) void prep_kernel(PrepTab t)
{
    __shared__ float tile[32][33];
    const int bid = blockIdx.x;
    int e = 0;
    while (e < 11 && bid >= t.blk0[e + 1]) ++e;
    const int local = bid - t.blk0[e];
    const int N = t.N[e];
    const int K = t.K[e];
    const int ntx = N >> 5;
    const int n0 = (local % ntx) * 32;
    const int k0 = (local / ntx) * 32;
    const float* __restrict__ W = t.src[e];
    __hip_bfloat16* __restrict__ D = t.dst[e];
    const int tx = threadIdx.x;
    const int ty = threadIdx.y;
    if (t.trans[e]) {
        for (int i = ty; i < 32; i += 8)
            tile[i][tx] = W[(size_t)(k0 + i) * N + n0 + tx];
        __syncthreads();
        for (int i = ty; i < 32; i += 8)
            D[(size_t)(n0 + i) * K + k0 + tx] = __float2bfloat16(tile[tx][i]);
    } else {
        for (int i = ty; i < 32; i += 8) {
            const size_t idx = (size_t)(k0 + i) * N + n0 + tx;
            D[idx] = __float2bfloat16(W[idx]);
        }
    }
}

// ---------------------------------------------------------------------------
// Pack 5 bias vectors (1024 f32 each) into bqkv1[3072] and bkv2[2048].
// ---------------------------------------------------------------------------
__global__ __launch_bounds__(256) void bias_pack_kernel(
    const float* __restrict__ bq1, const float* __restrict__ bk1,
    const float* __restrict__ bv1, const float* __restrict__ bk2,
    const float* __restrict__ bv2, float* __restrict__ bqkv1,
    float* __restrict__ bkv2)
{
    const int i = blockIdx.x * 256 + threadIdx.x;
    if (i < 1024)       bqkv1[i] = bq1[i];
    else if (i < 2048)  bqkv1[i] = bk1[i - 1024];
    else if (i < 3072)  bqkv1[i] = bv1[i - 2048];
    else if (i < 4096)  bkv2[i - 3072] = bk2[i - 3072];
    else if (i < 5120)  bkv2[i - 3072] = bv2[i - 4096];
}

// ---------------------------------------------------------------------------
// Row softmax over bf16 S, single-pass register-resident (N == 4096).
// ---------------------------------------------------------------------------
__global__ __launch_bounds__(256) void softmax_kernel(
    const __hip_bfloat16* __restrict__ S, __hip_bfloat16* __restrict__ A, int N, int causal)
{
    __shared__ float sm[4];
    const int row = blockIdx.x;
    const int tid = threadIdx.x;
    const int limit = causal ? (row + 1) : N;
    const int zl0 = (row & ~255) + 256;
    const int zlimit = causal ? (zl0 < N ? zl0 : N) : N;
    const __hip_bfloat16* Srow = S + (size_t)row * N;
    __hip_bfloat16* Arow = A + (size_t)row * N;

    float x[4][4];
    float m = -3.0e38f;
#pragma unroll
    for (int p = 0; p < 4; ++p) {
        const int cb = p * 1024 + tid * 4;
        if (cb < limit) {
            const bf16x4 xv = *(const bf16x4*)(Srow + cb);
#pragma unroll
            for (int e = 0; e < 4; ++e) {
                const float f = (cb + e < limit) ? (float)xv[e] : -3.0e38f;
                x[p][e] = f;
                m = fmaxf(m, f);
            }
        } else {
#pragma unroll
            for (int e = 0; e < 4; ++e) x[p][e] = -3.0e38f;
        }
    }
#pragma unroll
    for (int o = 32; o; o >>= 1) m = fmaxf(m, __shfl_down(m, o));
    if ((tid & 63) == 0) sm[tid >> 6] = m;
    __syncthreads();
    m = fmaxf(fmaxf(sm[0], sm[1]), fmaxf(sm[2], sm[3]));
    __syncthreads();

    float s = 0.f;
#pragma unroll
    for (int p = 0; p < 4; ++p) {
        const int cb = p * 1024 + tid * 4;
        if (cb < limit) {
#pragma unroll
            for (int e = 0; e < 4; ++e) {
                const float ev = (cb + e < limit) ? __expf(x[p][e] - m) : 0.f;
                x[p][e] = ev;
                s += ev;
            }
        } else {
#pragma unroll
            for (int e = 0; e < 4; ++e) x[p][e] = 0.f;
        }
    }
#pragma unroll
    for (int o = 32; o; o >>= 1) s += __shfl_down(s, o);
    if ((tid & 63) == 0) sm[tid >> 6] = s;
    __syncthreads();
    s = sm[0] + sm[1] + sm[2] + sm[3];
    const float inv = 1.f / s;

#pragma unroll
    for (int p = 0; p < 4; ++p) {
        const int cb = p * 1024 + tid * 4;
        if (cb < zlimit) {
            bf16x4 o = { (__bf16)(x[p][0] * inv), (__bf16)(x[p][1] * inv),
                         (__bf16)(x[p][2] * inv), (__bf16)(x[p][3] * inv) };
            *(bf16x4*)(Arow + cb) = o;
        }
    }
}

// ---------------------------------------------------------------------------
// Launch
// ---------------------------------------------------------------------------
extern "C" void kernel_launch(void* const* d_in, const int* in_sizes, int n_in,
                              void* d_out, int out_size, void* d_ws, size_t ws_size,
                              hipStream_t stream)
{
    const int M = 4096, Pd = 1024, DFF = 4096, NS = 4096;
    const size_t MB = 1024 * 1024;
    const int NOV = 0x40000000;   // "no V-transpose" sentinel column

    const float* Y   = (const float*)d_in[0];
    const float* Xp  = (const float*)d_in[1];
    const float* wq1 = (const float*)d_in[2];  const float* bq1 = (const float*)d_in[3];
    const float* wk1 = (const float*)d_in[4];  const float* bk1 = (const float*)d_in[5];
    const float* wv1 = (const float*)d_in[6];  const float* bv1 = (const float*)d_in[7];
    const float* w0  = (const float*)d_in[8];  const float* b0  = (const float*)d_in[9];
    const float* g1  = (const float*)d_in[10]; const float* be1 = (const float*)d_in[11];
    const float* wq2 = (const float*)d_in[12]; const float* bq2 = (const float*)d_in[13];
    const float* wk2 = (const float*)d_in[14]; const float* bk2 = (const float*)d_in[15];
    const float* wv2 = (const float*)d_in[16]; const float* bv2 = (const float*)d_in[17];
    const float* w1  = (const float*)d_in[18]; const float* b1  = (const float*)d_in[19];
    const float* g2  = (const float*)d_in[20]; const float* be2 = (const float*)d_in[21];
    const float* w2  = (const float*)d_in[22]; const float* b2  = (const float*)d_in[23];
    const float* w3  = (const float*)d_in[24]; const float* b3  = (const float*)d_in[25];
    const float* g3  = (const float*)d_in[26]; const float* be3 = (const float*)d_in[27];

    // ---- workspace layout ----
    char* ws = (char*)d_ws;
    __hip_bfloat16* Ybf   = (__hip_bfloat16*)(ws + 0 * MB);
    __hip_bfloat16* Ubf   = (__hip_bfloat16*)(ws + 0 * MB);
    __hip_bfloat16* Xpbf  = (__hip_bfloat16*)(ws + 8 * MB);
    __hip_bfloat16* AVbf  = (__hip_bfloat16*)(ws + 8 * MB);
    __hip_bfloat16* Qbf   = (__hip_bfloat16*)(ws + 8 * MB);
    __hip_bfloat16* wqkv1t= (__hip_bfloat16*)(ws + 16 * MB);
    __hip_bfloat16* w0t   = (__hip_bfloat16*)(ws + 22 * MB);
    __hip_bfloat16* wq2t  = (__hip_bfloat16*)(ws + 24 * MB);
    __hip_bfloat16* wkv2t = (__hip_bfloat16*)(ws + 26 * MB);
    __hip_bfloat16* w1t   = (__hip_bfloat16*)(ws + 30 * MB);
    __hip_bfloat16* w2t   = (__hip_bfloat16*)(ws + 32 * MB);
    __hip_bfloat16* w3t   = (__hip_bfloat16*)(ws + 40 * MB);
    float*          bqkv1 = (float*)(ws + 48 * MB);
    float*          bkv2  = (float*)(ws + 48 * MB + 512 * 1024);
    __hip_bfloat16* QKV1  = (__hip_bfloat16*)(ws + 49 * MB);
    __hip_bfloat16* KV2   = (__hip_bfloat16*)(ws + 73 * MB);
    __hip_bfloat16* Vt1   = (__hip_bfloat16*)(ws + 89 * MB);   // [Pd, M] bf16 = 8MB
    __hip_bfloat16* Sb    = (__hip_bfloat16*)(ws + 97 * MB);
    __hip_bfloat16* Pb    = (__hip_bfloat16*)(ws + 97 * MB);
    __hip_bfloat16* Abf   = (__hip_bfloat16*)(ws + 161 * MB);
    __hip_bfloat16* Vt2   = (__hip_bfloat16*)(ws + 193 * MB);  // [Pd, NS] bf16 = 8MB
    float*          Uf    = (float*)(ws + 209 * MB);
    float*          Out   = (float*)d_out;
    if (ws_size < 225 * MB) return;

    auto gemm = [&](const __hip_bfloat16* A, int lda, const __hip_bfloat16* Bt, int ldb,
                    int Mm, int Nn, int Kk, int ldc,
                    const float* bias, int bmode, float scale, const float* res,
                    int relu, int causal, int trap, int ksplit,
                    float* Cf, __hip_bfloat16* Cb) {
        const int nz = ksplit ? (Kk + ksplit - 1) / ksplit : 1;
        gemm_bt<<<dim3(Nn / 128, Mm / 128, nz), dim3(256), 0, stream>>>(
            A, lda, Bt, ldb, Mm, Nn, Kk, ldc, bias, bmode, scale, res, relu, causal, trap, ksplit,
            Cf, Cb, NOV, nullptr, 0,
            0, nullptr, nullptr, 0, 0, nullptr, nullptr, NOV, nullptr, 0);
    };
    auto gemm2 = [&](const __hip_bfloat16* A, int lda, const __hip_bfloat16* Bt, int ldb,
                     int Mm, int Nn, int Kk, int ldc,
                     const float* bias, int bmode, float scale,
                     int relu, int causal, int trap, int ksplit, __hip_bfloat16* Cb) {
        const int nz = ksplit ? (Kk + ksplit - 1) / ksplit : 1;
        gemm_bt2<<<dim3(Nn / 128, Mm / 256, nz), dim3(256), 0, stream>>>(
            A, lda, Bt, ldb, Mm, Nn, Kk, ldc, bias, bmode, scale, relu, causal, trap, ksplit, Cb);
    };
    auto gemm3 = [&](const __hip_bfloat16* A, int lda, const __hip_bfloat16* Bt, int ldb,
                     int Mm, int Nn, int Kk, int ldc,
                     const float* bias, int bmode, float scale,
                     int relu, int causal, int trap, int ksplit, __hip_bfloat16* Cb) {
        const int nz = ksplit ? (Kk + ksplit - 1) / ksplit : 1;
        gemm_bt3<<<dim3(Nn / 256, Mm / 256, nz), dim3(512), 0, stream>>>(
            A, lda, Bt, ldb, Mm, Nn, Kk, ldc, bias, bmode, scale, relu, causal, trap, ksplit, Cb);
    };
    auto reduce = [&](const __hip_bfloat16* P, int Mm, int Nn, int nsplit, int KC, int trapK,
                      const float* bias, const float* res, float* Cf, __hip_bfloat16* Cb) {
        reduce_k_kernel<<<dim3(Mm * Nn / 1024), dim3(256), 0, stream>>>(
            P, Mm, Nn, nsplit, KC, trapK, bias, res, Cf, Cb);
    };
    auto reduce_ln = [&](const __hip_bfloat16* P, int nsplit,
                         const float* bias, const float* res,
                         const float* gg, const float* bb,
                         float* outF, __hip_bfloat16* outB) {
        reduce_ln_kernel<<<dim3(M), dim3(256), 0, stream>>>(
            P, M, nsplit, bias, res, gg, bb, outF, outB);
    };

    const float scl = 0.03125f;  // 1/sqrt(1024)

    // --- prep: one batched dispatch for all transposes + converts ---
    {
        PrepTab t;
        const float* srcs[12]  = { wq1, wk1, wv1, w0, wq2, wk2, wv2, w1, w2, w3, Y, Xp };
        __hip_bfloat16* dsts[12] = { wqkv1t, wqkv1t + Pd * Pd, wqkv1t + 2 * Pd * Pd,
                                     w0t, wq2t, wkv2t, wkv2t + Pd * Pd, w1t,
                                     w2t, w3t, Ybf, Xpbf };
        const int Ks[12] = { Pd, Pd, Pd, Pd, Pd, Pd, Pd, Pd, Pd,  DFF, M,  NS };
        const int Ns[12] = { Pd, Pd, Pd, Pd, Pd, Pd, Pd, Pd, DFF, Pd,  Pd, Pd };
        const int trs[12] = { 1, 1, 1, 1, 1, 1, 1, 1, 1, 1, 0, 0 };
        int acc = 0;
        for (int e = 0; e < 12; ++e) {
            t.src[e] = srcs[e]; t.dst[e] = dsts[e];
            t.K[e] = Ks[e]; t.N[e] = Ns[e]; t.trans[e] = trs[e];
            t.blk0[e] = acc;
            acc += (Ns[e] / 32) * (Ks[e] / 32);
        }
        t.blk0[12] = acc;
        prep_kernel<<<dim3(acc), dim3(32, 8), 0, stream>>>(t);
    }
    bias_pack_kernel<<<dim3(20), dim3(256), 0, stream>>>(bq1, bk1, bv1, bk2, bv2, bqkv1, bkv2);

    // --- merged projections: QKV1 (24 n-blocks) + KV2 (16 n-blocks), 128-tile.
    //     V columns written transposed directly into Vt1 / Vt2. ---
    gemm_bt<<<dim3(40, 32, 1), dim3(256), 0, stream>>>(
        Ybf, Pd, wqkv1t, Pd, M, 3072, Pd, 3072, bqkv1, 1, 1.f, nullptr, 0, 0, 0, 0,
        nullptr, QKV1, 2048, Vt1, M,
        24, Xpbf, wkv2t, Pd, 2048, bkv2, KV2, 1024, Vt2, NS);

    // --- masked self-attention (ragged shapes stay on 256x128 kernel) ---
    gemm2(QKV1, 3072, QKV1 + 1024, 3072, M, M, Pd, M,
          nullptr, 0, scl, 0, 1, 0, 0, Sb);                      // causal S1
    softmax_kernel<<<dim3(M), dim3(256), 0, stream>>>(Sb, Abf, M, 1);
    gemm2(Abf, M, Vt1, M, M, Pd, M, Pd,
          nullptr, 0, 1.f, 0, 0, 1, 1024, Pb);                   // AV1 trapezoid splitK=4
    reduce(Pb, M, Pd, 4, 1024, M, nullptr, nullptr, nullptr, AVbf);
    gemm(AVbf, Pd, w0t, Pd, M, Pd, Pd, Pd,
         nullptr, 0, 1.f, nullptr, 0, 0, 0, 512, nullptr, Pb);   // w0 splitK=2
    reduce_ln(Pb, 2, b0, Y, g1, be1, Uf, Ubf);                   // + residual Y + LN1

    // --- cross-attention (uniform big shapes on 256x256 kernel) ---
    gemm(Ubf, Pd, wq2t, Pd, M, Pd, Pd, Pd,
         nullptr, 0, 1.f, nullptr, 0, 0, 0, 512, nullptr, Pb);   // wq2 splitK=2
    reduce(Pb, M, Pd, 2, 512, 0, bq2, nullptr, nullptr, Qbf);
    gemm3(Qbf, Pd, KV2, 2048, M, NS, Pd, NS,
          nullptr, 0, scl, 0, 0, 0, 0, Sb);                      // S2 (256x256, 16x16 grid)
    softmax_kernel<<<dim3(M), dim3(256), 0, stream>>>(Sb, Abf, NS, 0);
    gemm3(Abf, NS, Vt2, NS, M, Pd, NS, Pd,
          nullptr, 0, 1.f, 0, 0, 0, 1024, Pb);                   // AV2 splitK=4 (4x16x4)
    reduce(Pb, M, Pd, 4, 1024, 0, nullptr, nullptr, nullptr, AVbf);
    gemm(AVbf, Pd, w1t, Pd, M, Pd, Pd, Pd,
         nullptr, 0, 1.f, nullptr, 0, 0, 0, 512, nullptr, Pb);   // w1 splitK=2
    reduce_ln(Pb, 2, b1, Uf, g2, be2, Uf, Ubf);                  // + residual U1 + LN2

    // --- FFN (uniform big shapes on 256x256 kernel) ---
    gemm3(Ubf, Pd, w2t, Pd, M, DFF, Pd, DFF, b2, 1, 1.f, 1, 0, 0, 0, Abf);  // FFN1 relu (16x16)
    gemm3(Abf, DFF, w3t, DFF, M, Pd, DFF, Pd,
          nullptr, 0, 1.f, 0, 0, 0, 1024, Pb);                   // FFN2 splitK=4 (4x16x4)
    reduce_ln(Pb, 4, b3, Uf, g3, be3, Out, nullptr);             // + residual U2 + LN3
}

// Round 8
// 656.038 us; speedup vs baseline: 1.1219x; 1.0187x over previous
//
#include <hip/hip_runtime.h>
#include <hip/hip_bf16.h>

typedef __bf16 bf16x8 __attribute__((ext_vector_type(8)));
typedef __bf16 bf16x4 __attribute__((ext_vector_type(4)));
typedef float f32x4 __attribute__((ext_vector_type(4)));

#define AS1P(p) ((__attribute__((address_space(1))) void*)(void*)(p))
#define AS3P(p) ((__attribute__((address_space(3))) void*)(p))

// ---------------------------------------------------------------------------
// 128x128 bf16 GEMM (projections / thin-N): BK=32 triple-buffer, depth-2
// prefetch, single-barrier K-loop, XOR-swizzled LDS (conflict-free), XCD
// region swizzle. 48KB LDS -> 3 blocks/CU.
// MEASURED LOCAL OPTIMUM (76.5us projection). Round-6 lesson: depth-2
// prefetch with counted vmcnt is load-bearing — a 2-phase double-buffer
// variant (5 blocks/CU attempt) collapsed to 150us+. Do not shallow it.
// Round-7 analysis: BK/buffer-count reshuffles of this skeleton are
// isomorphic (same stage-ops, barriers, prefetch distance per K) — the only
// non-isomorphic upgrade is the full 8-phase fine interleave.
// V-columns (col >= vcol0) are written TRANSPOSED to Vt ([P, M] layout).
// ---------------------------------------------------------------------------
__global__ __launch_bounds__(256, 3) void gemm_bt(
    const __hip_bfloat16* __restrict__ A, int lda,
    const __hip_bfloat16* __restrict__ Bt, int ldb,
    int M, int N, int K, int ldc,
    const float* __restrict__ bias, int bias_mode,   // 0 none, 1 per-col, 2 per-row
    float scale,
    const float* __restrict__ residual,              // f32 [M,ldc] or null
    int relu, int causal_skip, int trapezoid, int ksplit,
    float* __restrict__ Cf, __hip_bfloat16* __restrict__ Cb,
    int vcol0, __hip_bfloat16* __restrict__ Vt, int ldvt,
    // fused second GEMM (blocks with nb >= nsplit1); shares lda/M/K
    int nsplit1, const __hip_bfloat16* __restrict__ A2,
    const __hip_bfloat16* __restrict__ Bt2, int ldb2, int ldc2,
    const float* __restrict__ bias2, __hip_bfloat16* __restrict__ Cb2,
    int vcol0_2, __hip_bfloat16* __restrict__ Vt2, int ldvt2)
{
    int nb = blockIdx.x;
    int mb = blockIdx.y;
    {   // XCD-aware 2D-region swizzle (identity if shape not divisible)
        const int gx = gridDim.x, gy = gridDim.y;
        if ((gx & 3) == 0 && (gy & 1) == 0) {
            const int id = mb * gx + nb;
            const int X  = id & 7;
            const int L  = id >> 3;
            const int rn = gx >> 2, rm = gy >> 1;
            const int nb_l = L / rm, mb_l = L - nb_l * rm;
            nb = (X & 3) * rn + nb_l;
            mb = (X >> 2) * rm + mb_l;
        }
    }
    if (nsplit1 && nb >= nsplit1) {
        A = A2; Bt = Bt2; ldb = ldb2; ldc = ldc2; bias = bias2;
        Cb = Cb2; Cf = nullptr; residual = nullptr;
        vcol0 = vcol0_2; Vt = Vt2; ldvt = ldvt2;
        nb -= nsplit1;
    }
    const int m_base = mb * 128;
    const int n_base = nb * 128;
    if (causal_skip && (n_base > m_base + 127)) return;
    int Kend = K;
    if (trapezoid) { int kl = m_base + 128; Kend = kl < K ? kl : K; }
    int kb = 0, ke = Kend;
    if (ksplit) {
        kb = blockIdx.z * ksplit;
        int k2 = kb + ksplit; ke = k2 < Kend ? k2 : Kend;
        if (kb >= ke) return;
        Cb += (size_t)blockIdx.z * M * ldc;
        Cf = nullptr;
    }
    const int nt = (ke - kb) >> 5;

    __shared__ __align__(16) __hip_bfloat16 Lds[3][8192];

    const int tid  = threadIdx.x;
    const int lane = tid & 63;
    const int wave = tid >> 6;
    const int wm = (wave >> 1) * 64;
    const int wn = (wave & 1) * 64;

    f32x4 acc[4][4];
#pragma unroll
    for (int i = 0; i < 4; ++i)
#pragma unroll
        for (int j = 0; j < 4; ++j) acc[i][j] = f32x4{0.f, 0.f, 0.f, 0.f};

    const bool isA = wave < 2;
    const __hip_bfloat16* G = isA ? (A + (size_t)m_base * lda) : (Bt + (size_t)n_base * ldb);
    const int ldg = isA ? lda : ldb;
    const int q0 = (wave & 1) * 4;
    const int rsub = lane >> 2;
    const int cx   = (lane & 3) ^ ((lane >> 3) & 3);
    const size_t grow = (size_t)(q0 * 16 + rsub) * ldg + (size_t)cx * 8 + kb;
    const int ldsoff = (isA ? 0 : 4096) + q0 * 512;

    const int lrow = lane & 15;
    const int cph  = ((lane >> 4) ^ ((lrow >> 1) & 3)) * 8;

#define ISSUE_TILE(KT, STG)                                                      \
    {                                                                            \
        const __hip_bfloat16* g = G + grow + (size_t)(KT) * 32;                  \
        __hip_bfloat16* dst = &Lds[STG][ldsoff];                                 \
        _Pragma("unroll")                                                        \
        for (int q = 0; q < 4; ++q) {                                            \
            __builtin_amdgcn_global_load_lds(AS1P(g), AS3P(dst), 16, 0, 0);      \
            g += (size_t)16 * ldg; dst += 512;                                   \
        }                                                                        \
    }

    ISSUE_TILE(0, 0)
    if (nt > 1) ISSUE_TILE(1, 1)

    int cur = 0;
    for (int kt = 0; kt < nt; ++kt) {
        __builtin_amdgcn_sched_barrier(0);
        if (kt + 1 < nt) __builtin_amdgcn_s_waitcnt(0x0F74);  // vmcnt(4)
        else             __builtin_amdgcn_s_waitcnt(0x0F70);  // vmcnt(0)
        __builtin_amdgcn_sched_barrier(0);
        __builtin_amdgcn_s_barrier();
        __builtin_amdgcn_sched_barrier(0);
        if (kt + 2 < nt) {
            int s2 = cur + 2; if (s2 >= 3) s2 -= 3;
            ISSUE_TILE(kt + 2, s2)
        }

        bf16x8 af[4], bfv[4];
#pragma unroll
        for (int i = 0; i < 4; ++i)
            af[i] = *(const bf16x8*)&Lds[cur][(wm + i * 16 + lrow) * 32 + cph];
#pragma unroll
        for (int j = 0; j < 4; ++j)
            bfv[j] = *(const bf16x8*)&Lds[cur][4096 + (wn + j * 16 + lrow) * 32 + cph];
#pragma unroll
        for (int i = 0; i < 4; ++i)
#pragma unroll
            for (int j = 0; j < 4; ++j)
                acc[i][j] = __builtin_amdgcn_mfma_f32_16x16x32_bf16(af[i], bfv[j], acc[i][j], 0, 0, 0);

        cur = (cur + 1 == 3) ? 0 : cur + 1;
    }
#undef ISSUE_TILE

    const int r0 = (lane >> 4) * 4;
    const int c0 = lane & 15;
    const bool vtrans = (n_base >= vcol0);   // vcol0 multiple of 128 -> block-uniform
#pragma unroll
    for (int i = 0; i < 4; ++i) {
#pragma unroll
        for (int j = 0; j < 4; ++j) {
            const int col = n_base + wn + j * 16 + c0;
            const int row0 = m_base + wm + i * 16 + r0;
            float vv[4];
#pragma unroll
            for (int r = 0; r < 4; ++r) {
                float v = acc[i][j][r] * scale;
                if (bias_mode == 1) v += bias[col];
                else if (bias_mode == 2) v += bias[row0 + r];
                if (relu) v = fmaxf(v, 0.f);
                vv[r] = v;
            }
            if (vtrans) {
                bf16x4 o = { (__bf16)vv[0], (__bf16)vv[1], (__bf16)vv[2], (__bf16)vv[3] };
                *(bf16x4*)(Vt + (size_t)(col - vcol0) * ldvt + row0) = o;
            } else {
#pragma unroll
                for (int r = 0; r < 4; ++r) {
                    const size_t idx = (size_t)(row0 + r) * ldc + col;
                    float v = vv[r];
                    if (residual) v += residual[idx];
                    if (Cf) Cf[idx] = v;
                    else    Cb[idx] = __float2bfloat16(v);
                }
            }
        }
    }
}

// ---------------------------------------------------------------------------
// 256x128 bf16 GEMM: 4 waves each 128x64, BK=32 triple-buffer (72KB LDS,
// 2 blocks/CU), depth-2 prefetch, single barrier per iter. Used for the
// ragged attention shapes (causal S1 / trapezoid AV1).
// ---------------------------------------------------------------------------
__global__ __launch_bounds__(256, 2) void gemm_bt2(
    const __hip_bfloat16* __restrict__ A, int lda,
    const __hip_bfloat16* __restrict__ Bt, int ldb,
    int M, int N, int K, int ldc,
    const float* __restrict__ bias, int bias_mode,
    float scale,
    int relu, int causal_skip, int trapezoid, int ksplit,
    __hip_bfloat16* __restrict__ Cb)
{
    int nb = blockIdx.x;
    int mb = blockIdx.y;
    {   // XCD-aware 2D-region swizzle
        const int gx = gridDim.x, gy = gridDim.y;
        if ((gx & 3) == 0 && (gy & 1) == 0) {
            const int id = mb * gx + nb;
            const int X  = id & 7;
            const int L  = id >> 3;
            const int rn = gx >> 2, rm = gy >> 1;
            const int nb_l = L / rm, mb_l = L - nb_l * rm;
            nb = (X & 3) * rn + nb_l;
            mb = (X >> 2) * rm + mb_l;
        }
    }
    const int m_base = mb * 256;
    const int n_base = nb * 128;
    if (causal_skip && (n_base > m_base + 255)) return;
    int Kend = K;
    if (trapezoid) { int kl = m_base + 256; Kend = kl < K ? kl : K; }
    int kb = 0, ke = Kend;
    if (ksplit) {
        kb = blockIdx.z * ksplit;
        int k2 = kb + ksplit; ke = k2 < Kend ? k2 : Kend;
        if (kb >= ke) return;
        Cb += (size_t)blockIdx.z * M * ldc;
    }
    const int nt = (ke - kb) >> 5;

    // [stage][ A 256x32 (8192 elems) | B 128x32 (4096 elems) ] = 3 x 24 KB
    __shared__ __align__(16) __hip_bfloat16 Lds[3][12288];

    const int tid  = threadIdx.x;
    const int lane = tid & 63;
    const int wave = tid >> 6;
    const int wtm = (wave >> 1) * 128;
    const int wtn = (wave & 1) * 64;

    f32x4 acc[8][4];
#pragma unroll
    for (int i = 0; i < 8; ++i)
#pragma unroll
        for (int j = 0; j < 4; ++j) acc[i][j] = f32x4{0.f, 0.f, 0.f, 0.f};

    const int rsub = lane >> 2;
    const int cx   = (lane & 3) ^ ((lane >> 3) & 3);
    const __hip_bfloat16* GA = A  + (size_t)(m_base + wave * 64) * lda + (size_t)rsub * lda + (size_t)cx * 8 + kb;
    const __hip_bfloat16* GB = Bt + (size_t)(n_base + wave * 32) * ldb + (size_t)rsub * ldb + (size_t)cx * 8 + kb;
    const int ldsA = wave * 2048;
    const int ldsB = 8192 + wave * 1024;

    const int lrow = lane & 15;
    const int cph  = ((lane >> 4) ^ ((lrow >> 1) & 3)) * 8;

#define ISSUE_TILE2(KT, STG)                                                     \
    {                                                                            \
        const size_t ko = (size_t)(KT) * 32;                                     \
        const __hip_bfloat16* ga = GA + ko;                                      \
        __hip_bfloat16* da = &Lds[STG][ldsA];                                    \
        _Pragma("unroll")                                                        \
        for (int q = 0; q < 4; ++q) {                                            \
            __builtin_amdgcn_global_load_lds(AS1P(ga), AS3P(da), 16, 0, 0);      \
            ga += (size_t)16 * lda; da += 512;                                   \
        }                                                                        \
        const __hip_bfloat16* gb = GB + ko;                                      \
        __hip_bfloat16* db = &Lds[STG][ldsB];                                    \
        _Pragma("unroll")                                                        \
        for (int q = 0; q < 2; ++q) {                                            \
            __builtin_amdgcn_global_load_lds(AS1P(gb), AS3P(db), 16, 0, 0);      \
            gb += (size_t)16 * ldb; db += 512;                                   \
        }                                                                        \
    }

    ISSUE_TILE2(0, 0)
    if (nt > 1) ISSUE_TILE2(1, 1)

    int cur = 0;
    for (int kt = 0; kt < nt; ++kt) {
        __builtin_amdgcn_sched_barrier(0);
        if (kt + 1 < nt) __builtin_amdgcn_s_waitcnt(0x0F76);  // vmcnt(6)
        else             __builtin_amdgcn_s_waitcnt(0x0F70);  // vmcnt(0)
        __builtin_amdgcn_sched_barrier(0);
        __builtin_amdgcn_s_barrier();
        __builtin_amdgcn_sched_barrier(0);
        if (kt + 2 < nt) {
            int s2 = cur + 2; if (s2 >= 3) s2 -= 3;
            ISSUE_TILE2(kt + 2, s2)
        }

        bf16x8 af[8], bfv[4];
#pragma unroll
        for (int i = 0; i < 8; ++i)
            af[i] = *(const bf16x8*)&Lds[cur][(wtm + i * 16 + lrow) * 32 + cph];
#pragma unroll
        for (int j = 0; j < 4; ++j)
            bfv[j] = *(const bf16x8*)&Lds[cur][8192 + (wtn + j * 16 + lrow) * 32 + cph];
#pragma unroll
        for (int i = 0; i < 8; ++i)
#pragma unroll
            for (int j = 0; j < 4; ++j)
                acc[i][j] = __builtin_amdgcn_mfma_f32_16x16x32_bf16(af[i], bfv[j], acc[i][j], 0, 0, 0);

        cur = (cur + 1 == 3) ? 0 : cur + 1;
    }
#undef ISSUE_TILE2

    const int r0 = (lane >> 4) * 4;
    const int c0 = lane & 15;
#pragma unroll
    for (int i = 0; i < 8; ++i) {
#pragma unroll
        for (int j = 0; j < 4; ++j) {
            const int col = n_base + wtn + j * 16 + c0;
#pragma unroll
            for (int r = 0; r < 4; ++r) {
                const int row = m_base + wtm + i * 16 + r0 + r;
                float v = acc[i][j][r] * scale;
                if (bias_mode == 1) v += bias[col];
                else if (bias_mode == 2) v += bias[row];
                if (relu) v = fmaxf(v, 0.f);
                Cb[(size_t)row * ldc + col] = __float2bfloat16(v);
            }
        }
    }
}

// ---------------------------------------------------------------------------
// 256x256 bf16 GEMM (big uniform shapes): 8 waves (512 thr) in a 2x4 layout,
// each wave 128x64 out. BK=32, triple-buffer (96KB LDS, 1 block/CU), depth-2
// prefetch, single barrier per iter.
// ---------------------------------------------------------------------------
__global__ __launch_bounds__(512, 2) void gemm_bt3(
    const __hip_bfloat16* __restrict__ A, int lda,
    const __hip_bfloat16* __restrict__ Bt, int ldb,
    int M, int N, int K, int ldc,
    const float* __restrict__ bias, int bias_mode,
    float scale,
    int relu, int causal_skip, int trapezoid, int ksplit,
    __hip_bfloat16* __restrict__ Cb)
{
    int nb = blockIdx.x;
    int mb = blockIdx.y;
    {   // XCD-aware 2D-region swizzle
        const int gx = gridDim.x, gy = gridDim.y;
        if ((gx & 3) == 0 && (gy & 1) == 0) {
            const int id = mb * gx + nb;
            const int X  = id & 7;
            const int L  = id >> 3;
            const int rn = gx >> 2, rm = gy >> 1;
            const int nb_l = L / rm, mb_l = L - nb_l * rm;
            nb = (X & 3) * rn + nb_l;
            mb = (X >> 2) * rm + mb_l;
        }
    }
    const int m_base = mb * 256;
    const int n_base = nb * 256;
    if (causal_skip && (n_base > m_base + 255)) return;
    int Kend = K;
    if (trapezoid) { int kl = m_base + 256; Kend = kl < K ? kl : K; }
    int kb = 0, ke = Kend;
    if (ksplit) {
        kb = blockIdx.z * ksplit;
        int k2 = kb + ksplit; ke = k2 < Kend ? k2 : Kend;
        if (kb >= ke) return;
        Cb += (size_t)blockIdx.z * M * ldc;
    }
    const int nt = (ke - kb) >> 5;

    // [stage][ A 256x32 (8192 elems) | B 256x32 (8192 elems) ] = 3 x 32 KB
    __shared__ __align__(16) __hip_bfloat16 Lds[3][16384];

    const int tid  = threadIdx.x;
    const int lane = tid & 63;
    const int wave = tid >> 6;          // 0..7
    const int wtm = (wave >> 2) * 128;
    const int wtn = (wave & 3) * 64;

    f32x4 acc[8][4];
#pragma unroll
    for (int i = 0; i < 8; ++i)
#pragma unroll
        for (int j = 0; j < 4; ++j) acc[i][j] = f32x4{0.f, 0.f, 0.f, 0.f};

    const int rsub = lane >> 2;
    const int cx   = (lane & 3) ^ ((lane >> 3) & 3);
    const __hip_bfloat16* GA = A  + (size_t)(m_base + wave * 32 + rsub) * lda + (size_t)cx * 8 + kb;
    const __hip_bfloat16* GB = Bt + (size_t)(n_base + wave * 32 + rsub) * ldb + (size_t)cx * 8 + kb;
    const int ldsA = wave * 1024;
    const int ldsB = 8192 + wave * 1024;

    const int lrow = lane & 15;
    const int cph  = ((lane >> 4) ^ ((lrow >> 1) & 3)) * 8;

#define ISSUE_TILE3(KT, STG)                                                     \
    {                                                                            \
        const size_t ko = (size_t)(KT) * 32;                                     \
        const __hip_bfloat16* ga = GA + ko;                                      \
        __hip_bfloat16* da = &Lds[STG][ldsA];                                    \
        _Pragma("unroll")                                                        \
        for (int q = 0; q < 2; ++q) {                                            \
            __builtin_amdgcn_global_load_lds(AS1P(ga), AS3P(da), 16, 0, 0);      \
            ga += (size_t)16 * lda; da += 512;                                   \
        }                                                                        \
        const __hip_bfloat16* gb = GB + ko;                                      \
        __hip_bfloat16* db = &Lds[STG][ldsB];                                    \
        _Pragma("unroll")                                                        \
        for (int q = 0; q < 2; ++q) {                                            \
            __builtin_amdgcn_global_load_lds(AS1P(gb), AS3P(db), 16, 0, 0);      \
            gb += (size_t)16 * ldb; db += 512;                                   \
        }                                                                        \
    }

    ISSUE_TILE3(0, 0)
    if (nt > 1) ISSUE_TILE3(1, 1)

    int cur = 0;
    for (int kt = 0; kt < nt; ++kt) {
        __builtin_amdgcn_sched_barrier(0);
        if (kt + 1 < nt) __builtin_amdgcn_s_waitcnt(0x0F74);  // vmcnt(4)
        else             __builtin_amdgcn_s_waitcnt(0x0F70);  // vmcnt(0)
        __builtin_amdgcn_sched_barrier(0);
        __builtin_amdgcn_s_barrier();
        __builtin_amdgcn_sched_barrier(0);
        if (kt + 2 < nt) {
            int s2 = cur + 2; if (s2 >= 3) s2 -= 3;
            ISSUE_TILE3(kt + 2, s2)
        }

        bf16x8 af[8], bfv[4];
#pragma unroll
        for (int i = 0; i < 8; ++i)
            af[i] = *(const bf16x8*)&Lds[cur][(wtm + i * 16 + lrow) * 32 + cph];
#pragma unroll
        for (int j = 0; j < 4; ++j)
            bfv[j] = *(const bf16x8*)&Lds[cur][8192 + (wtn + j * 16 + lrow) * 32 + cph];
#pragma unroll
        for (int i = 0; i < 8; ++i)
#pragma unroll
            for (int j = 0; j < 4; ++j)
                acc[i][j] = __builtin_amdgcn_mfma_f32_16x16x32_bf16(af[i], bfv[j], acc[i][j], 0, 0, 0);

        cur = (cur + 1 == 3) ? 0 : cur + 1;
    }
#undef ISSUE_TILE3

    const int r0 = (lane >> 4) * 4;
    const int c0 = lane & 15;
#pragma unroll
    for (int i = 0; i < 8; ++i) {
#pragma unroll
        for (int j = 0; j < 4; ++j) {
            const int col = n_base + wtn + j * 16 + c0;
#pragma unroll
            for (int r = 0; r < 4; ++r) {
                const int row = m_base + wtm + i * 16 + r0 + r;
                float v = acc[i][j][r] * scale;
                if (bias_mode == 1) v += bias[col];
                else if (bias_mode == 2) v += bias[row];
                if (relu) v = fmaxf(v, 0.f);
                Cb[(size_t)row * ldc + col] = __float2bfloat16(v);
            }
        }
    }
}

// ---------------------------------------------------------------------------
// Split-K reducer over bf16 partials: C = epi( sum_z Pb[z] )
// 16 B/lane vectorized: 8 cols/thread (G13 coalescing sweet spot).
// ---------------------------------------------------------------------------
__global__ __launch_bounds__(256) void reduce_k_kernel(
    const __hip_bfloat16* __restrict__ Pb, int M, int N, int nsplit, int KC, int trapK,
    const float* __restrict__ bias, const float* __restrict__ residual,
    float* __restrict__ Cf, __hip_bfloat16* __restrict__ Cb)
{
    const int idx = blockIdx.x * 256 + threadIdx.x;
    const int nv = N >> 3;
    const int row = idx / nv;
    if (row >= M) return;
    const int c8 = (idx - row * nv) * 8;
    int nc = nsplit;
    if (trapK) {
        int kend = (row & ~255) + 256; if (kend > trapK) kend = trapK;
        nc = (kend + KC - 1) / KC;
    }
    float s[8];
#pragma unroll
    for (int e = 0; e < 8; ++e) s[e] = 0.f;
    for (int c = 0; c < nc; ++c) {
        const bf16x8 p = *(const bf16x8*)(Pb + ((size_t)c * M + row) * N + c8);
#pragma unroll
        for (int e = 0; e < 8; ++e) s[e] += (float)p[e];
    }
    if (bias) {
        const f32x4 b0 = *(const f32x4*)(bias + c8);
        const f32x4 b1 = *(const f32x4*)(bias + c8 + 4);
#pragma unroll
        for (int e = 0; e < 4; ++e) { s[e] += b0[e]; s[e + 4] += b1[e]; }
    }
    if (residual) {
        const f32x4 r0 = *(const f32x4*)(residual + (size_t)row * N + c8);
        const f32x4 r1 = *(const f32x4*)(residual + (size_t)row * N + c8 + 4);
#pragma unroll
        for (int e = 0; e < 4; ++e) { s[e] += r0[e]; s[e + 4] += r1[e]; }
    }
    if (Cf) {
        f32x4 o0 = { s[0], s[1], s[2], s[3] };
        f32x4 o1 = { s[4], s[5], s[6], s[7] };
        *(f32x4*)(Cf + (size_t)row * N + c8) = o0;
        *(f32x4*)(Cf + (size_t)row * N + c8 + 4) = o1;
    } else {
        bf16x8 o = { (__bf16)s[0], (__bf16)s[1], (__bf16)s[2], (__bf16)s[3],
                     (__bf16)s[4], (__bf16)s[5], (__bf16)s[6], (__bf16)s[7] };
        *(bf16x8*)(Cb + (size_t)row * N + c8) = o;
    }
}

// ---------------------------------------------------------------------------
// Fused split-K reduce + bias + residual + row LayerNorm over 1024.
// ---------------------------------------------------------------------------
__global__ __launch_bounds__(256) void reduce_ln_kernel(
    const __hip_bfloat16* __restrict__ Pb, int M, int nsplit,
    const float* __restrict__ bias, const float* __restrict__ residual,
    const float* __restrict__ g, const float* __restrict__ b,
    float* __restrict__ outF, __hip_bfloat16* __restrict__ outB)
{
    __shared__ float sm[8];
    const int row = blockIdx.x;
    const int tid = threadIdx.x;
    const int c4 = tid * 4;

    float v0 = 0.f, v1 = 0.f, v2 = 0.f, v3 = 0.f;
    for (int c = 0; c < nsplit; ++c) {
        const bf16x4 p = *(const bf16x4*)(Pb + ((size_t)c * M + row) * 1024 + c4);
        v0 += (float)p[0]; v1 += (float)p[1]; v2 += (float)p[2]; v3 += (float)p[3];
    }
    {
        const f32x4 bv = *(const f32x4*)(bias + c4);
        v0 += bv[0]; v1 += bv[1]; v2 += bv[2]; v3 += bv[3];
    }
    {
        const f32x4 rv = *(const f32x4*)(residual + (size_t)row * 1024 + c4);
        v0 += rv[0]; v1 += rv[1]; v2 += rv[2]; v3 += rv[3];
    }

    float s  = v0 + v1 + v2 + v3;
    float ss = v0 * v0 + v1 * v1 + v2 * v2 + v3 * v3;
#pragma unroll
    for (int o = 32; o; o >>= 1) { s += __shfl_down(s, o); ss += __shfl_down(ss, o); }
    if ((tid & 63) == 0) { sm[tid >> 6] = s; sm[4 + (tid >> 6)] = ss; }
    __syncthreads();
    s  = sm[0] + sm[1] + sm[2] + sm[3];
    ss = sm[4] + sm[5] + sm[6] + sm[7];
    const float mu   = s * (1.f / 1024.f);
    const float var  = ss * (1.f / 1024.f) - mu * mu;
    const float rstd = rsqrtf(var + 1e-5f);
    const float4 gv = ((const float4*)g)[tid];
    const float4 bv = ((const float4*)b)[tid];
    float4 o;
    o.x = (v0 - mu) * rstd * gv.x + bv.x;
    o.y = (v1 - mu) * rstd * gv.y + bv.y;
    o.z = (v2 - mu) * rstd * gv.z + bv.z;
    o.w = (v3 - mu) * rstd * gv.w + bv.w;
    ((float4*)(outF + (size_t)row * 1024))[tid] = o;
    if (outB) {
        bf16x4 ob = { (__bf16)o.x, (__bf16)o.y, (__bf16)o.z, (__bf16)o.w };
        *(bf16x4*)(outB + (size_t)row * 1024 + c4) = ob;
    }
}

// ---------------------------------------------------------------------------
// Batched prep: weight transposes (f32 [K,N] -> bf16 [N,K], trans=1),
// straight f32->bf16 converts (trans=0), and f32 1024-elem copies (trans=2,
// bias packing) in ONE dispatch. 17 entries.
// ---------------------------------------------------------------------------
struct PrepTab {
    const float* src[17];
    __hip_bfloat16* dst[17];
    int K[17];
    int N[17];
    int trans[17];
    int blk0[18];
};

__global__ __launch_bounds__(256) void prep_kernel(PrepTab t)
{
    __shared__ float tile[32][33];
    const int bid = blockIdx.x;
    int e = 0;
    while (e < 16 && bid >= t.blk0[e + 1]) ++e;
    const int local = bid - t.blk0[e];
    const float* __restrict__ W = t.src[e];
    const int tx = threadIdx.x;
    const int ty = threadIdx.y;
    if (t.trans[e] == 2) {          // f32 1024-elem copy (bias pack); 1 block
        float* __restrict__ Df = (float*)t.dst[e];
        const int i = ty * 32 + tx;
        ((float4*)Df)[i] = ((const float4*)W)[i];
        return;
    }
    const int N = t.N[e];
    const int K = t.K[e];
    const int ntx = N >> 5;
    const int n0 = (local % ntx) * 32;
    const int k0 = (local / ntx) * 32;
    __hip_bfloat16* __restrict__ D = t.dst[e];
    if (t.trans[e] == 1) {
        for (int i = ty; i < 32; i += 8)
            tile[i][tx] = W[(size_t)(k0 + i) * N + n0 + tx];
        __syncthreads();
        for (int i = ty; i < 32; i += 8)
            D[(size_t)(n0 + i) * K + k0 + tx] = __float2bfloat16(tile[tx][i]);
    } else {
        for (int i = ty; i < 32; i += 8) {
            const size_t idx = (size_t)(k0 + i) * N + n0 + tx;
            D[idx] = __float2bfloat16(W[idx]);
        }
    }
}

// ---------------------------------------------------------------------------
// Row softmax over bf16 S, single-pass register-resident (N == 4096).
// ---------------------------------------------------------------------------
__global__ __launch_bounds__(256) void softmax_kernel(
    const __hip_bfloat16* __restrict__ S, __hip_bfloat16* __restrict__ A, int N, int causal)
{
    __shared__ float sm[4];
    const int row = blockIdx.x;
    const int tid = threadIdx.x;
    const int limit = causal ? (row + 1) : N;
    const int zl0 = (row & ~255) + 256;
    const int zlimit = causal ? (zl0 < N ? zl0 : N) : N;
    const __hip_bfloat16* Srow = S + (size_t)row * N;
    __hip_bfloat16* Arow = A + (size_t)row * N;

    float x[4][4];
    float m = -3.0e38f;
#pragma unroll
    for (int p = 0; p < 4; ++p) {
        const int cb = p * 1024 + tid * 4;
        if (cb < limit) {
            const bf16x4 xv = *(const bf16x4*)(Srow + cb);
#pragma unroll
            for (int e = 0; e < 4; ++e) {
                const float f = (cb + e < limit) ? (float)xv[e] : -3.0e38f;
                x[p][e] = f;
                m = fmaxf(m, f);
            }
        } else {
#pragma unroll
            for (int e = 0; e < 4; ++e) x[p][e] = -3.0e38f;
        }
    }
#pragma unroll
    for (int o = 32; o; o >>= 1) m = fmaxf(m, __shfl_down(m, o));
    if ((tid & 63) == 0) sm[tid >> 6] = m;
    __syncthreads();
    m = fmaxf(fmaxf(sm[0], sm[1]), fmaxf(sm[2], sm[3]));
    __syncthreads();

    float s = 0.f;
#pragma unroll
    for (int p = 0; p < 4; ++p) {
        const int cb = p * 1024 + tid * 4;
        if (cb < limit) {
#pragma unroll
            for (int e = 0; e < 4; ++e) {
                const float ev = (cb + e < limit) ? __expf(x[p][e] - m) : 0.f;
                x[p][e] = ev;
                s += ev;
            }
        } else {
#pragma unroll
            for (int e = 0; e < 4; ++e) x[p][e] = 0.f;
        }
    }
#pragma unroll
    for (int o = 32; o; o >>= 1) s += __shfl_down(s, o);
    if ((tid & 63) == 0) sm[tid >> 6] = s;
    __syncthreads();
    s = sm[0] + sm[1] + sm[2] + sm[3];
    const float inv = 1.f / s;

#pragma unroll
    for (int p = 0; p < 4; ++p) {
        const int cb = p * 1024 + tid * 4;
        if (cb < zlimit) {
            bf16x4 o = { (__bf16)(x[p][0] * inv), (__bf16)(x[p][1] * inv),
                         (__bf16)(x[p][2] * inv), (__bf16)(x[p][3] * inv) };
            *(bf16x4*)(Arow + cb) = o;
        }
    }
}

// ---------------------------------------------------------------------------
// Launch
// ---------------------------------------------------------------------------
extern "C" void kernel_launch(void* const* d_in, const int* in_sizes, int n_in,
                              void* d_out, int out_size, void* d_ws, size_t ws_size,
                              hipStream_t stream)
{
    const int M = 4096, Pd = 1024, DFF = 4096, NS = 4096;
    const size_t MB = 1024 * 1024;
    const int NOV = 0x40000000;   // "no V-transpose" sentinel column

    const float* Y   = (const float*)d_in[0];
    const float* Xp  = (const float*)d_in[1];
    const float* wq1 = (const float*)d_in[2];  const float* bq1 = (const float*)d_in[3];
    const float* wk1 = (const float*)d_in[4];  const float* bk1 = (const float*)d_in[5];
    const float* wv1 = (const float*)d_in[6];  const float* bv1 = (const float*)d_in[7];
    const float* w0  = (const float*)d_in[8];  const float* b0  = (const float*)d_in[9];
    const float* g1  = (const float*)d_in[10]; const float* be1 = (const float*)d_in[11];
    const float* wq2 = (const float*)d_in[12]; const float* bq2 = (const float*)d_in[13];
    const float* wk2 = (const float*)d_in[14]; const float* bk2 = (const float*)d_in[15];
    const float* wv2 = (const float*)d_in[16]; const float* bv2 = (const float*)d_in[17];
    const float* w1  = (const float*)d_in[18]; const float* b1  = (const float*)d_in[19];
    const float* g2  = (const float*)d_in[20]; const float* be2 = (const float*)d_in[21];
    const float* w2  = (const float*)d_in[22]; const float* b2  = (const float*)d_in[23];
    const float* w3  = (const float*)d_in[24]; const float* b3  = (const float*)d_in[25];
    const float* g3  = (const float*)d_in[26]; const float* be3 = (const float*)d_in[27];

    // ---- workspace layout ----
    char* ws = (char*)d_ws;
    __hip_bfloat16* Ybf   = (__hip_bfloat16*)(ws + 0 * MB);
    __hip_bfloat16* Ubf   = (__hip_bfloat16*)(ws + 0 * MB);
    __hip_bfloat16* Xpbf  = (__hip_bfloat16*)(ws + 8 * MB);
    __hip_bfloat16* AVbf  = (__hip_bfloat16*)(ws + 8 * MB);
    __hip_bfloat16* Qbf   = (__hip_bfloat16*)(ws + 8 * MB);
    __hip_bfloat16* wqkv1t= (__hip_bfloat16*)(ws + 16 * MB);
    __hip_bfloat16* w0t   = (__hip_bfloat16*)(ws + 22 * MB);
    __hip_bfloat16* wq2t  = (__hip_bfloat16*)(ws + 24 * MB);
    __hip_bfloat16* wkv2t = (__hip_bfloat16*)(ws + 26 * MB);
    __hip_bfloat16* w1t   = (__hip_bfloat16*)(ws + 30 * MB);
    __hip_bfloat16* w2t   = (__hip_bfloat16*)(ws + 32 * MB);
    __hip_bfloat16* w3t   = (__hip_bfloat16*)(ws + 40 * MB);
    float*          bqkv1 = (float*)(ws + 48 * MB);
    float*          bkv2  = (float*)(ws + 48 * MB + 512 * 1024);
    __hip_bfloat16* QKV1  = (__hip_bfloat16*)(ws + 49 * MB);
    __hip_bfloat16* KV2   = (__hip_bfloat16*)(ws + 73 * MB);
    __hip_bfloat16* Vt1   = (__hip_bfloat16*)(ws + 89 * MB);   // [Pd, M] bf16 = 8MB
    __hip_bfloat16* Sb    = (__hip_bfloat16*)(ws + 97 * MB);
    __hip_bfloat16* Pb    = (__hip_bfloat16*)(ws + 97 * MB);
    __hip_bfloat16* Abf   = (__hip_bfloat16*)(ws + 161 * MB);
    __hip_bfloat16* Vt2   = (__hip_bfloat16*)(ws + 193 * MB);  // [Pd, NS] bf16 = 8MB
    float*          Uf    = (float*)(ws + 209 * MB);
    float*          Out   = (float*)d_out;
    if (ws_size < 225 * MB) return;

    auto gemm = [&](const __hip_bfloat16* A, int lda, const __hip_bfloat16* Bt, int ldb,
                    int Mm, int Nn, int Kk, int ldc,
                    const float* bias, int bmode, float scale, const float* res,
                    int relu, int causal, int trap, int ksplit,
                    float* Cf, __hip_bfloat16* Cb) {
        const int nz = ksplit ? (Kk + ksplit - 1) / ksplit : 1;
        gemm_bt<<<dim3(Nn / 128, Mm / 128, nz), dim3(256), 0, stream>>>(
            A, lda, Bt, ldb, Mm, Nn, Kk, ldc, bias, bmode, scale, res, relu, causal, trap, ksplit,
            Cf, Cb, NOV, nullptr, 0,
            0, nullptr, nullptr, 0, 0, nullptr, nullptr, NOV, nullptr, 0);
    };
    auto gemm2 = [&](const __hip_bfloat16* A, int lda, const __hip_bfloat16* Bt, int ldb,
                     int Mm, int Nn, int Kk, int ldc,
                     const float* bias, int bmode, float scale,
                     int relu, int causal, int trap, int ksplit, __hip_bfloat16* Cb) {
        const int nz = ksplit ? (Kk + ksplit - 1) / ksplit : 1;
        gemm_bt2<<<dim3(Nn / 128, Mm / 256, nz), dim3(256), 0, stream>>>(
            A, lda, Bt, ldb, Mm, Nn, Kk, ldc, bias, bmode, scale, relu, causal, trap, ksplit, Cb);
    };
    auto gemm3 = [&](const __hip_bfloat16* A, int lda, const __hip_bfloat16* Bt, int ldb,
                     int Mm, int Nn, int Kk, int ldc,
                     const float* bias, int bmode, float scale,
                     int relu, int causal, int trap, int ksplit, __hip_bfloat16* Cb) {
        const int nz = ksplit ? (Kk + ksplit - 1) / ksplit : 1;
        gemm_bt3<<<dim3(Nn / 256, Mm / 256, nz), dim3(512), 0, stream>>>(
            A, lda, Bt, ldb, Mm, Nn, Kk, ldc, bias, bmode, scale, relu, causal, trap, ksplit, Cb);
    };
    auto reduce = [&](const __hip_bfloat16* P, int Mm, int Nn, int nsplit, int KC, int trapK,
                      const float* bias, const float* res, float* Cf, __hip_bfloat16* Cb) {
        reduce_k_kernel<<<dim3(Mm * Nn / 2048), dim3(256), 0, stream>>>(
            P, Mm, Nn, nsplit, KC, trapK, bias, res, Cf, Cb);
    };
    auto reduce_ln = [&](const __hip_bfloat16* P, int nsplit,
                         const float* bias, const float* res,
                         const float* gg, const float* bb,
                         float* outF, __hip_bfloat16* outB) {
        reduce_ln_kernel<<<dim3(M), dim3(256), 0, stream>>>(
            P, M, nsplit, bias, res, gg, bb, outF, outB);
    };

    const float scl = 0.03125f;  // 1/sqrt(1024)

    // --- prep: one batched dispatch for all transposes + converts + bias pack ---
    {
        PrepTab t;
        const float* srcs[17]  = { wq1, wk1, wv1, w0, wq2, wk2, wv2, w1, w2, w3, Y, Xp,
                                   bq1, bk1, bv1, bk2, bv2 };
        __hip_bfloat16* dsts[17] = { wqkv1t, wqkv1t + Pd * Pd, wqkv1t + 2 * Pd * Pd,
                                     w0t, wq2t, wkv2t, wkv2t + Pd * Pd, w1t,
                                     w2t, w3t, Ybf, Xpbf,
                                     (__hip_bfloat16*)bqkv1, (__hip_bfloat16*)(bqkv1 + Pd),
                                     (__hip_bfloat16*)(bqkv1 + 2 * Pd),
                                     (__hip_bfloat16*)bkv2, (__hip_bfloat16*)(bkv2 + Pd) };
        const int Ks[17] = { Pd, Pd, Pd, Pd, Pd, Pd, Pd, Pd, Pd,  DFF, M,  NS, 0,0,0,0,0 };
        const int Ns[17] = { Pd, Pd, Pd, Pd, Pd, Pd, Pd, Pd, DFF, Pd,  Pd, Pd, 0,0,0,0,0 };
        const int trs[17] = { 1, 1, 1, 1, 1, 1, 1, 1, 1, 1, 0, 0, 2, 2, 2, 2, 2 };
        int acc = 0;
        for (int e = 0; e < 17; ++e) {
            t.src[e] = srcs[e]; t.dst[e] = dsts[e];
            t.K[e] = Ks[e]; t.N[e] = Ns[e]; t.trans[e] = trs[e];
            t.blk0[e] = acc;
            acc += (trs[e] == 2) ? 1 : (Ns[e] / 32) * (Ks[e] / 32);
        }
        t.blk0[17] = acc;
        prep_kernel<<<dim3(acc), dim3(32, 8), 0, stream>>>(t);
    }

    // --- merged projections: QKV1 (24 n-blocks) + KV2 (16 n-blocks), 128-tile.
    //     V columns written transposed directly into Vt1 / Vt2. ---
    gemm_bt<<<dim3(40, 32, 1), dim3(256), 0, stream>>>(
        Ybf, Pd, wqkv1t, Pd, M, 3072, Pd, 3072, bqkv1, 1, 1.f, nullptr, 0, 0, 0, 0,
        nullptr, QKV1, 2048, Vt1, M,
        24, Xpbf, wkv2t, Pd, 2048, bkv2, KV2, 1024, Vt2, NS);

    // --- masked self-attention (ragged shapes stay on 256x128 kernel) ---
    gemm2(QKV1, 3072, QKV1 + 1024, 3072, M, M, Pd, M,
          nullptr, 0, scl, 0, 1, 0, 0, Sb);                      // causal S1
    softmax_kernel<<<dim3(M), dim3(256), 0, stream>>>(Sb, Abf, M, 1);
    gemm2(Abf, M, Vt1, M, M, Pd, M, Pd,
          nullptr, 0, 1.f, 0, 0, 1, 1024, Pb);                   // AV1 trapezoid splitK=4
    reduce(Pb, M, Pd, 4, 1024, M, nullptr, nullptr, nullptr, AVbf);
    gemm(AVbf, Pd, w0t, Pd, M, Pd, Pd, Pd,
         nullptr, 0, 1.f, nullptr, 0, 0, 0, 512, nullptr, Pb);   // w0 splitK=2
    reduce_ln(Pb, 2, b0, Y, g1, be1, Uf, Ubf);                   // + residual Y + LN1

    // --- cross-attention (uniform big shapes on 256x256 kernel) ---
    gemm(Ubf, Pd, wq2t, Pd, M, Pd, Pd, Pd,
         nullptr, 0, 1.f, nullptr, 0, 0, 0, 512, nullptr, Pb);   // wq2 splitK=2
    reduce(Pb, M, Pd, 2, 512, 0, bq2, nullptr, nullptr, Qbf);
    gemm3(Qbf, Pd, KV2, 2048, M, NS, Pd, NS,
          nullptr, 0, scl, 0, 0, 0, 0, Sb);                      // S2 (256x256, 16x16 grid)
    softmax_kernel<<<dim3(M), dim3(256), 0, stream>>>(Sb, Abf, NS, 0);
    gemm3(Abf, NS, Vt2, NS, M, Pd, NS, Pd,
          nullptr, 0, 1.f, 0, 0, 0, 1024, Pb);                   // AV2 splitK=4 (4x16x4)
    reduce(Pb, M, Pd, 4, 1024, 0, nullptr, nullptr, nullptr, AVbf);
    gemm(AVbf, Pd, w1t, Pd, M, Pd, Pd, Pd,
         nullptr, 0, 1.f, nullptr, 0, 0, 0, 512, nullptr, Pb);   // w1 splitK=2
    reduce_ln(Pb, 2, b1, Uf, g2, be2, Uf, Ubf);                  // + residual U1 + LN2

    // --- FFN (uniform big shapes on 256x256 kernel) ---
    gemm3(Ubf, Pd, w2t, Pd, M, DFF, Pd, DFF, b2, 1, 1.f, 1, 0, 0, 0, Abf);  // FFN1 relu (16x16)
    gemm3(Abf, DFF, w3t, DFF, M, Pd, DFF, Pd,
          nullptr, 0, 1.f, 0, 0, 0, 1024, Pb);                   // FFN2 splitK=4 (4x16x4)
    reduce_ln(Pb, 4, b3, Uf, g3, be3, Out, nullptr);             // + residual U2 + LN3
}